// Round 15
// baseline (982.909 us; speedup 1.0000x reference)
//
#include <hip/hip_runtime.h>
#include <math.h>

// Problem constants
#define NIMG 8
#define MDIM 512
#define IMGE (MDIM*MDIM)        // 262144 per image
#define TOT  (NIMG*IMGE)        // 2097152 complex elements
#define BETA_K 4096
#define LAMD 0.1

typedef double2 c64;

struct SelState { unsigned int known; unsigned int rank; unsigned int thrkey; };

// Key derivation — used identically everywhere (rowC store, rowFA/rowD recompute):
// from the ROUNDED f32 components, sqrt in f64, result cast to f32 bits.
__device__ __forceinline__ unsigned int keyOf(float bx, float by){
    return __float_as_uint((float)sqrt((double)bx*(double)bx + (double)by*(double)by));
}

// ---------------- LDS addressing ----------------
// Swizzle XORs bits 1..3 only (bit 0 preserved -> f64 pairs stay ordered-adjacent,
// ds_*_b128 vectorization preserved).
__device__ __forceinline__ int LPOS(int ln, int q){
    return (ln << 9) + (q ^ ((((q >> 4) ^ (2 * ln)) & 7) << 1));
}
__device__ __forceinline__ int rev8(int n){   // base-8 digit reversal of 9-bit index
    return ((n & 7) << 6) | (n & 56) | (n >> 6);
}
__device__ __forceinline__ int rde(int w, int k){ // rev8(8w+k)
    return 64*k + 8*(w & 7) + (w >> 3);
}

// ---------------- 8-point DFT in registers. INV=true: conjugate (inverse) ----------------
template<bool INV>
__device__ __forceinline__ void dft8(double* xr, double* xi){
    const double C = 0.70710678118654752440;
    double t0r=xr[0]+xr[4], t0i=xi[0]+xi[4];
    double t1r=xr[0]-xr[4], t1i=xi[0]-xi[4];
    double t2r=xr[2]+xr[6], t2i=xi[2]+xi[6];
    double t3r=xr[2]-xr[6], t3i=xi[2]-xi[6];
    double m3r = INV ? -t3i : t3i;
    double m3i = INV ?  t3r : -t3r;
    double E0r=t0r+t2r, E0i=t0i+t2i;
    double E2r=t0r-t2r, E2i=t0i-t2i;
    double E1r=t1r+m3r, E1i=t1i+m3i;
    double E3r=t1r-m3r, E3i=t1i-m3i;
    double u0r=xr[1]+xr[5], u0i=xi[1]+xi[5];
    double u1r=xr[1]-xr[5], u1i=xi[1]-xi[5];
    double u2r=xr[3]+xr[7], u2i=xi[3]+xi[7];
    double u3r=xr[3]-xr[7], u3i=xi[3]-xi[7];
    double n3r = INV ? -u3i : u3i;
    double n3i = INV ?  u3r : -u3r;
    double O0r=u0r+u2r, O0i=u0i+u2i;
    double O2r=u0r-u2r, O2i=u0i-u2i;
    double O1r=u1r+n3r, O1i=u1i+n3i;
    double O3r=u1r-n3r, O3i=u1i-n3i;
    double W1r = INV ? C*(O1r - O1i) : C*(O1r + O1i);
    double W1i = INV ? C*(O1r + O1i) : C*(O1i - O1r);
    double W2r = INV ? -O2i : O2i;
    double W2i = INV ?  O2r : -O2r;
    double W3r = INV ? -C*(O3r + O3i) : C*(O3i - O3r);
    double W3i = INV ? C*(O3r - O3i) : -C*(O3r + O3i);
    xr[0]=E0r+O0r; xi[0]=E0i+O0i;  xr[4]=E0r-O0r; xi[4]=E0i-O0i;
    xr[1]=E1r+W1r; xi[1]=E1i+W1i;  xr[5]=E1r-W1r; xi[5]=E1i-W1i;
    xr[2]=E2r+W2r; xi[2]=E2i+W2i;  xr[6]=E2r-W2r; xi[6]=E2i-W2i;
    xr[3]=E3r+W3r; xi[3]=E3i+W3i;  xr[7]=E3r-W3r; xi[7]=E3i-W3i;
}

// ================= ROW-path FFT helpers (register ends) =================
template<bool INV>
__device__ __forceinline__ void dit_from_regs(double (&ar)[2][8], double (&ai)[2][8],
                                              double* re, double* im, const c64* __restrict__ tw){
    const int t=threadIdx.x, w=t&63, l0=t>>6;
    #pragma unroll
    for (int h=0;h<2;++h){
        dft8<INV>(ar[h], ai[h]);
        const int ln=l0+4*h;
        #pragma unroll
        for (int k=0;k<8;++k){ int p=LPOS(ln,8*w+k); re[p]=ar[h][k]; im[p]=ai[h][k]; }
    }
    __syncthreads();
    {   // stage 1: groups 64g+j+8k, twiddle tw[8jk]
        const int g=w>>3, j=w&7;
        double wr[8], wi[8];
        #pragma unroll
        for (int k=1;k<8;++k){ c64 tv=tw[8*j*k]; wr[k]=tv.x; wi[k]=INV?-tv.y:tv.y; }
        #pragma unroll
        for (int h=0;h<2;++h){
            const int ln=l0+4*h;
            double xr[8], xi[8];
            #pragma unroll
            for (int k=0;k<8;++k){ int p=LPOS(ln,64*g+j+8*k); double a=re[p],b=im[p];
                if(k==0){xr[0]=a; xi[0]=b;} else {xr[k]=a*wr[k]-b*wi[k]; xi[k]=a*wi[k]+b*wr[k];} }
            dft8<INV>(xr,xi);
            #pragma unroll
            for (int k=0;k<8;++k){ int p=LPOS(ln,64*g+j+8*k); re[p]=xr[k]; im[p]=xi[k]; }
        }
    }
    __syncthreads();
    {   // stage 2 -> regs: groups j+64k, twiddle tw[jk]
        const int j=w;
        double wr[8], wi[8];
        #pragma unroll
        for (int k=1;k<8;++k){ c64 tv=tw[j*k]; wr[k]=tv.x; wi[k]=INV?-tv.y:tv.y; }
        #pragma unroll
        for (int h=0;h<2;++h){
            const int ln=l0+4*h;
            #pragma unroll
            for (int k=0;k<8;++k){ int p=LPOS(ln,j+64*k); double a=re[p],b=im[p];
                if(k==0){ar[h][0]=a; ai[h][0]=b;} else {ar[h][k]=a*wr[k]-b*wi[k]; ai[h][k]=a*wi[k]+b*wr[k];} }
            dft8<INV>(ar[h], ai[h]);
        }
    }
}

template<bool INV>
__device__ __forceinline__ void dif_to_regs(double (&ar)[2][8], double (&ai)[2][8],
                                            double* re, double* im, const c64* __restrict__ tw){
    const int t=threadIdx.x, w=t&63, l0=t>>6;
    {   // stage A (from regs): dft8, post-twiddle tw[w*k], write at j+64k
        const int j=w;
        double wr[8], wi[8];
        #pragma unroll
        for (int k=1;k<8;++k){ c64 tv=tw[j*k]; wr[k]=tv.x; wi[k]=INV?-tv.y:tv.y; }
        #pragma unroll
        for (int h=0;h<2;++h){
            dft8<INV>(ar[h], ai[h]);
            const int ln=l0+4*h;
            #pragma unroll
            for (int k=0;k<8;++k){
                int p=LPOS(ln,j+64*k);
                if(k==0){ re[p]=ar[h][0]; im[p]=ai[h][0]; }
                else { re[p]=ar[h][k]*wr[k]-ai[h][k]*wi[k]; im[p]=ar[h][k]*wi[k]+ai[h][k]*wr[k]; }
            }
        }
    }
    __syncthreads();
    {   // stage B: groups 64g+j+8k, post-twiddle tw[8jk]
        const int g=w>>3, j=w&7;
        double wr[8], wi[8];
        #pragma unroll
        for (int k=1;k<8;++k){ c64 tv=tw[8*j*k]; wr[k]=tv.x; wi[k]=INV?-tv.y:tv.y; }
        #pragma unroll
        for (int h=0;h<2;++h){
            const int ln=l0+4*h;
            double xr[8], xi[8];
            #pragma unroll
            for (int k=0;k<8;++k){ int p=LPOS(ln,64*g+j+8*k); xr[k]=re[p]; xi[k]=im[p]; }
            dft8<INV>(xr,xi);
            #pragma unroll
            for (int k=0;k<8;++k){
                int p=LPOS(ln,64*g+j+8*k);
                if(k==0){ re[p]=xr[0]; im[p]=xi[0]; }
                else { re[p]=xr[k]*wr[k]-xi[k]*wi[k]; im[p]=xr[k]*wi[k]+xi[k]*wr[k]; }
            }
        }
    }
    __syncthreads();
    // stage C -> regs (no twiddle)
    #pragma unroll
    for (int h=0;h<2;++h){
        const int ln=l0+4*h;
        #pragma unroll
        for (int k=0;k<8;++k){ int p=LPOS(ln,8*w+k); ar[h][k]=re[p]; ai[h][k]=im[p]; }
        dft8<INV>(ar[h], ai[h]);
    }
}

// ================= COL-path FFT (full-LDS) =================
template<bool INV>
__device__ void r8_dit(double* re, double* im, const c64* __restrict__ tw){
    const int t = threadIdx.x;
    const int w = t & 63;
    const int l0 = t >> 6;
    __syncthreads();
    #pragma unroll
    for (int h = 0; h < 2; ++h){
        const int ln = l0 + 4*h;
        double xr[8], xi[8];
        #pragma unroll
        for (int k = 0; k < 8; ++k){ int p = LPOS(ln, 8*w + k); xr[k]=re[p]; xi[k]=im[p]; }
        dft8<INV>(xr, xi);
        #pragma unroll
        for (int k = 0; k < 8; ++k){ int p = LPOS(ln, 8*w + k); re[p]=xr[k]; im[p]=xi[k]; }
    }
    {
        const int g = w >> 3, j = w & 7;
        double wr[8], wi[8];
        #pragma unroll
        for (int k = 1; k < 8; ++k){ c64 tv = tw[8*j*k]; wr[k]=tv.x; wi[k]= INV ? -tv.y : tv.y; }
        __syncthreads();
        #pragma unroll
        for (int h = 0; h < 2; ++h){
            const int ln = l0 + 4*h;
            double xr[8], xi[8];
            #pragma unroll
            for (int k = 0; k < 8; ++k){
                int p = LPOS(ln, 64*g + j + 8*k); double a=re[p], b=im[p];
                if (k == 0){ xr[0]=a; xi[0]=b; }
                else { xr[k]=a*wr[k]-b*wi[k]; xi[k]=a*wi[k]+b*wr[k]; }
            }
            dft8<INV>(xr, xi);
            #pragma unroll
            for (int k = 0; k < 8; ++k){ int p = LPOS(ln, 64*g + j + 8*k); re[p]=xr[k]; im[p]=xi[k]; }
        }
    }
    {
        const int j = w;
        double wr[8], wi[8];
        #pragma unroll
        for (int k = 1; k < 8; ++k){ c64 tv = tw[j*k]; wr[k]=tv.x; wi[k]= INV ? -tv.y : tv.y; }
        __syncthreads();
        #pragma unroll
        for (int h = 0; h < 2; ++h){
            const int ln = l0 + 4*h;
            double xr[8], xi[8];
            #pragma unroll
            for (int k = 0; k < 8; ++k){
                int p = LPOS(ln, j + 64*k); double a=re[p], b=im[p];
                if (k == 0){ xr[0]=a; xi[0]=b; }
                else { xr[k]=a*wr[k]-b*wi[k]; xi[k]=a*wi[k]+b*wr[k]; }
            }
            dft8<INV>(xr, xi);
            #pragma unroll
            for (int k = 0; k < 8; ++k){ int p = LPOS(ln, j + 64*k); re[p]=xr[k]; im[p]=xi[k]; }
        }
    }
}

template<bool INV>
__device__ void r8_dif(double* re, double* im, const c64* __restrict__ tw){
    const int t = threadIdx.x;
    const int w = t & 63;
    const int l0 = t >> 6;
    {
        const int j = w;
        double wr[8], wi[8];
        #pragma unroll
        for (int k = 1; k < 8; ++k){ c64 tv = tw[j*k]; wr[k]=tv.x; wi[k]= INV ? -tv.y : tv.y; }
        __syncthreads();
        #pragma unroll
        for (int h = 0; h < 2; ++h){
            const int ln = l0 + 4*h;
            double xr[8], xi[8];
            #pragma unroll
            for (int k = 0; k < 8; ++k){ int p = LPOS(ln, j + 64*k); xr[k]=re[p]; xi[k]=im[p]; }
            dft8<INV>(xr, xi);
            #pragma unroll
            for (int k = 0; k < 8; ++k){
                int p = LPOS(ln, j + 64*k);
                if (k == 0){ re[p]=xr[0]; im[p]=xi[0]; }
                else { re[p]=xr[k]*wr[k]-xi[k]*wi[k]; im[p]=xr[k]*wi[k]+xi[k]*wr[k]; }
            }
        }
    }
    {
        const int g = w >> 3, j = w & 7;
        double wr[8], wi[8];
        #pragma unroll
        for (int k = 1; k < 8; ++k){ c64 tv = tw[8*j*k]; wr[k]=tv.x; wi[k]= INV ? -tv.y : tv.y; }
        __syncthreads();
        #pragma unroll
        for (int h = 0; h < 2; ++h){
            const int ln = l0 + 4*h;
            double xr[8], xi[8];
            #pragma unroll
            for (int k = 0; k < 8; ++k){ int p = LPOS(ln, 64*g + j + 8*k); xr[k]=re[p]; xi[k]=im[p]; }
            dft8<INV>(xr, xi);
            #pragma unroll
            for (int k = 0; k < 8; ++k){
                int p = LPOS(ln, 64*g + j + 8*k);
                if (k == 0){ re[p]=xr[0]; im[p]=xi[0]; }
                else { re[p]=xr[k]*wr[k]-xi[k]*wi[k]; im[p]=xr[k]*wi[k]+xi[k]*wr[k]; }
            }
        }
    }
    __syncthreads();
    #pragma unroll
    for (int h = 0; h < 2; ++h){
        const int ln = l0 + 4*h;
        double xr[8], xi[8];
        #pragma unroll
        for (int k = 0; k < 8; ++k){ int p = LPOS(ln, 8*w + k); xr[k]=re[p]; xi[k]=im[p]; }
        dft8<INV>(xr, xi);
        #pragma unroll
        for (int k = 0; k < 8; ++k){ int p = LPOS(ln, 8*w + k); re[p]=xr[k]; im[p]=xi[k]; }
    }
}

__device__ __forceinline__ void col_load32(const float2* __restrict__ src, size_t base,
                                           double* re, double* im){
    const int t = threadIdx.x;
    #pragma unroll
    for (int it = 0; it < 16; ++it){
        int idx = it*256 + t; int ln = idx & 7, e = idx >> 3;
        float2 v = src[base + ln + (size_t)e*512];
        int p = LPOS(ln, rev8(e));
        re[p] = (double)v.x; im[p] = (double)v.y;
    }
}

// ---------------- init: T = exp(i*(z/WL)*Q) (f64), twiddles (f64) ----------------
__global__ __launch_bounds__(256) void k_init(const float* __restrict__ Q,
                                              const float* __restrict__ zp,
                                              c64* __restrict__ T,
                                              c64* __restrict__ tw){
    int i = blockIdx.x*256 + threadIdx.x;
    if (i < IMGE){
        double a = ((double)zp[0] / 6.37e-07) * (double)Q[i];
        T[i] = make_double2(cos(a), sin(a));
    }
    if (i < 512){
        double a = -6.283185307179586476925286766559 * ((double)i / 512.0);
        tw[i] = make_double2(cos(a), sin(a));
    }
}

// ---------------- k_colF (iter 1): forward col FFT of H -> t2 ----------------
__global__ __launch_bounds__(256,2) void k_colF(const float2* __restrict__ H,
                                                float2* __restrict__ t2,
                                                const c64* __restrict__ tw){
    __shared__ double re[4096]; __shared__ double im[4096];
    const int t = threadIdx.x, blk = blockIdx.x;
    const size_t base = (size_t)(blk >> 6) * IMGE + (size_t)(blk & 63) * 8;
    col_load32(H, base, re, im);
    r8_dit<false>(re, im, tw);
    __syncthreads();
    #pragma unroll
    for (int it = 0; it < 16; ++it){
        int idx = it*256 + t; int ln = idx & 7, e = idx >> 3;
        int p = LPOS(ln, e);
        t2[base + ln + (size_t)e*512] = make_float2((float)re[p], (float)im[p]);
    }
}

// ---------------- k_rowFA: rowF(X) -> G=FX*T (store); then rowI(G + Bm) -> t2 ----------------
__global__ __launch_bounds__(256,2) void k_rowFA(float2* __restrict__ t2,
                                                 const float2* __restrict__ B,
                                                 const SelState* __restrict__ st,
                                                 const c64* __restrict__ T,
                                                 float2* __restrict__ G,
                                                 const c64* __restrict__ tw){
    __shared__ double re[4096]; __shared__ double im[4096];
    const int t = threadIdx.x, blk = blockIdx.x;
    const int w = t & 63, l0 = t >> 6;
    const size_t base = (size_t)blk * 4096;
    const unsigned int thr = st->thrkey;
    double ar[2][8], ai[2][8];
    #pragma unroll
    for (int h=0;h<2;++h){ const int ln=l0+4*h;
        #pragma unroll
        for (int k=0;k<8;++k){ float2 v = t2[base + ln*512 + rde(w,k)];
            ar[h][k]=(double)v.x; ai[h][k]=(double)v.y; } }
    dit_from_regs<false>(ar, ai, re, im, tw);      // rowF of colF(X): full fft2(X) rows
    #pragma unroll
    for (int h=0;h<2;++h){
        const int ln=l0+4*h;
        const int u = (blk & 63) * 8 + ln;
        #pragma unroll
        for (int k=0;k<8;++k){
            const int e = w + 64*k;
            size_t addr = base + ln*512 + e;
            c64 tv = T[u*512 + e];
            double xr = ar[h][k], xi = ai[h][k];
            double gr = xr*tv.x - xi*tv.y;         // G = fft2(X)*T
            double gi = xr*tv.y + xi*tv.x;
            G[addr] = make_float2((float)gr, (float)gi);
            float2 b = B[addr];
            bool keep = keyOf(b.x, b.y) >= thr;    // Bm = top-k kept (key recomputed)
            ar[h][k] = gr + (keep ? (double)b.x : 0.0);
            ai[h][k] = gi + (keep ? (double)b.y : 0.0);
        }
    }
    dif_to_regs<true>(ar, ai, re, im, tw);         // rowI(G + Bm)
    const double sc = 1.0/512.0;
    #pragma unroll
    for (int h=0;h<2;++h){ const int ln=l0+4*h;
        #pragma unroll
        for (int k=0;k<8;++k)
            t2[base + ln*512 + rde(w,k)] = make_float2((float)(ar[h][k]*sc), (float)(ai[h][k]*sc)); }
}

// ---------------- kB: colI -> W=normalize(Z) -> Qc=H*W -> colF(Qc) ----------------
template<bool FINAL>
__global__ __launch_bounds__(256,2) void k_colWQ(float2* __restrict__ t2,
                                                 const float2* __restrict__ H,
                                                 float2* __restrict__ outW,
                                                 const c64* __restrict__ tw){
    __shared__ double re[4096]; __shared__ double im[4096];
    const int t = threadIdx.x, blk = blockIdx.x;
    const size_t base = (size_t)(blk >> 6) * IMGE + (size_t)(blk & 63) * 8;
    col_load32(t2, base, re, im);
    r8_dit<true>(re, im, tw);          // inverse col FFT (unscaled here)
    __syncthreads();
    const double sc = 1.0/512.0;
    #pragma unroll
    for (int it = 0; it < 16; ++it){
        int idx = it*256 + t; int ln = idx & 7, e = idx >> 3;
        size_t addr = base + ln + (size_t)e*512;
        int p = LPOS(ln, e);
        double zr = re[p]*sc, zi = im[p]*sc;   // Z = convXT + IB (spatial)
        double m = sqrt(zr*zr + zi*zi);
        double d = (m == 0.0) ? 1.0 : m;
        double wx = zr/d, wy = zi/d;           // W = normalize(Z)
        if (FINAL) outW[addr] = make_float2((float)wx, (float)wy);
        float2 h = H[addr];
        re[p] = (double)h.x*wx - (double)h.y*wy;   // Qc = H*W
        im[p] = (double)h.x*wy + (double)h.y*wx;
    }
    r8_dif<false>(re, im, tw);         // forward col FFT of Qc
    __syncthreads();
    #pragma unroll
    for (int it = 0; it < 16; ++it){
        int idx = it*256 + t; int ln = idx & 7, e = idx >> 3;
        int p = LPOS(ln, rev8(e));
        t2[base + ln + (size_t)e*512] = make_float2((float)re[p], (float)im[p]);
    }
}

// ---------------- kC: rowF -> B = FQc - G -> store B/keys + fused hist pass-1 ----------------
template<bool G0>
__global__ __launch_bounds__(256,2) void k_rowC(const float2* __restrict__ t2,
                                                const float2* __restrict__ G,
                                                float2* __restrict__ B,
                                                unsigned int* __restrict__ keys,
                                                unsigned int* __restrict__ hist,
                                                const c64* __restrict__ tw){
    __shared__ double re[4096]; __shared__ double im[4096];
    const int t = threadIdx.x, blk = blockIdx.x;
    const int w = t & 63, l0 = t >> 6;
    const size_t base = (size_t)blk * 4096;
    double ar[2][8], ai[2][8];
    #pragma unroll
    for (int h=0;h<2;++h){ const int ln=l0+4*h;
        #pragma unroll
        for (int k=0;k<8;++k){ float2 v = t2[base + ln*512 + rde(w,k)];
            ar[h][k]=(double)v.x; ai[h][k]=(double)v.y; } }
    dit_from_regs<false>(ar, ai, re, im, tw);
    __syncthreads();                   // stage-2 LDS reads done -> reuse re as hist
    unsigned int* lh = reinterpret_cast<unsigned int*>(re);
    for (int b = t; b < 2048; b += 256) lh[b] = 0u;
    __syncthreads();
    #pragma unroll
    for (int h=0;h<2;++h){
        const int ln=l0+4*h;
        #pragma unroll
        for (int k=0;k<8;++k){
            size_t addr = base + ln*512 + (w + 64*k);
            double br = ar[h][k], bi = ai[h][k];
            if (!G0){ float2 g = G[addr]; br -= (double)g.x; bi -= (double)g.y; }
            float fbr = (float)br, fbi = (float)bi;
            B[addr] = make_float2(fbr, fbi);
            unsigned int key = keyOf(fbr, fbi);    // from ROUNDED f32 (matches consumers)
            keys[addr] = key;
            atomicAdd(&lh[key >> 21], 1u);
        }
    }
    __syncthreads();
    for (int b = t; b < 2048; b += 256){
        unsigned int v = lh[b];
        if (v) atomicAdd(&hist[b], v);
    }
}

// ---------------- kD: E = (B*(1-mask) + G)*conj(T) -> rowI -> t2 (x1/512) ----------------
template<bool G0>
__global__ __launch_bounds__(256,2) void k_rowD(const float2* __restrict__ B,
                                                const SelState* __restrict__ st,
                                                const float2* __restrict__ G,
                                                const c64* __restrict__ T,
                                                float2* __restrict__ t2,
                                                const c64* __restrict__ tw){
    __shared__ double re[4096]; __shared__ double im[4096];
    const int t = threadIdx.x, blk = blockIdx.x;
    const int w = t & 63, l0 = t >> 6;
    const size_t base = (size_t)blk * 4096;
    const unsigned int thr = st->thrkey;
    double ar[2][8], ai[2][8];
    #pragma unroll
    for (int h=0;h<2;++h){
        const int ln=l0+4*h;
        const int u = (blk & 63) * 8 + ln;
        #pragma unroll
        for (int k=0;k<8;++k){
            const int e = w + 64*k;
            size_t addr = base + ln*512 + e;
            float2 b = B[addr];
            bool lo = keyOf(b.x, b.y) < thr;      // complement of top-k mask (key recomputed)
            double vr = lo ? (double)b.x : 0.0;
            double vi = lo ? (double)b.y : 0.0;
            if (!G0){ float2 g = G[addr]; vr += (double)g.x; vi += (double)g.y; }
            c64 tv = T[u*512 + e];
            ar[h][k] = vr*tv.x + vi*tv.y;         // * conj(T)
            ai[h][k] = vi*tv.x - vr*tv.y;
        }
    }
    dif_to_regs<true>(ar, ai, re, im, tw);
    const double sc = 1.0/512.0;
    #pragma unroll
    for (int h=0;h<2;++h){ const int ln=l0+4*h;
        #pragma unroll
        for (int k=0;k<8;++k)
            t2[base + ln*512 + rde(w,k)] = make_float2((float)(ar[h][k]*sc), (float)(ai[h][k]*sc)); }
}

// ---------------- kE: colI -> X = inp1*(|inp1|>LAM) -> colF(X) ----------------
__global__ __launch_bounds__(256,2) void k_colX(float2* __restrict__ t2,
                                                const c64* __restrict__ tw){
    __shared__ double re[4096]; __shared__ double im[4096];
    const int t = threadIdx.x, blk = blockIdx.x;
    const size_t base = (size_t)(blk >> 6) * IMGE + (size_t)(blk & 63) * 8;
    col_load32(t2, base, re, im);
    r8_dit<true>(re, im, tw);
    __syncthreads();
    const double sc = 1.0/512.0;
    #pragma unroll
    for (int it = 0; it < 16; ++it){
        int idx = it*256 + t;
        int p = LPOS(idx & 7, idx >> 3);
        double vr = re[p]*sc, vi = im[p]*sc;      // inp1
        double m = sqrt(vr*vr + vi*vi);
        bool keep = m > LAMD;
        re[p] = keep ? vr : 0.0;
        im[p] = keep ? vi : 0.0;
    }
    r8_dif<false>(re, im, tw);
    __syncthreads();
    #pragma unroll
    for (int it = 0; it < 16; ++it){
        int idx = it*256 + t; int ln = idx & 7, e = idx >> 3;
        int p = LPOS(ln, rev8(e));
        t2[base + ln + (size_t)e*512] = make_float2((float)re[p], (float)im[p]);
    }
}

// ---------------- final masked B -> d_out second half ----------------
__global__ __launch_bounds__(256) void k_outB(const float2* __restrict__ B,
                                              const unsigned int* __restrict__ keys,
                                              const SelState* __restrict__ st,
                                              float2* __restrict__ outB){
    int i = blockIdx.x*256 + threadIdx.x;
    float2 v = B[i];
    if (keys[i] < st->thrkey) v = make_float2(0.0f, 0.0f);
    outB[i] = v;
}

// ---------------- select pass 1 scan (hist from k_rowC); zeroes candCnt ----------------
__global__ __launch_bounds__(256) void k_scan1(unsigned int* __restrict__ hist,
                                               SelState* __restrict__ st,
                                               unsigned int* __restrict__ candCnt){
    __shared__ unsigned int s[256];
    const int t = threadIdx.x;
    unsigned c[8];
    unsigned local = 0u;
    const int b0 = t * 8;
    #pragma unroll
    for (int j = 0; j < 8; ++j){
        unsigned v = hist[b0 + j]; hist[b0 + j] = 0u;
        c[j] = v; local += v;
    }
    if (t == 0) *candCnt = 0u;
    s[t] = local;
    __syncthreads();
    #pragma unroll
    for (int off = 1; off < 256; off <<= 1){
        unsigned add = (t + off < 256) ? s[t + off] : 0u;
        __syncthreads();
        s[t] += add;
        __syncthreads();
    }
    unsigned rank = (unsigned)BETA_K;
    unsigned stot   = s[t];
    unsigned sAfter = (t < 255) ? s[t + 1] : 0u;
    if (sAfter < rank && stot >= rank){
        unsigned cum = sAfter;
        int j = 7;
        #pragma unroll
        for (int k = 7; k >= 0; --k){
            j = k;
            if (cum + c[k] >= rank) break;
            cum += c[k];
        }
        st->rank  = rank - cum;
        st->known = (unsigned)(b0 + j);
    }
}

// ---------------- compact (LDS-staged): keys with top-11 bits == st->known -> cand ----------------
// 1024 blocks x 256 thr, each block covers exactly 2048 keys (512 uint4) -> LDS buf bound 2048.
// LDS atomics for intra-block slots; ONE global atomicAdd per block; coalesced copy-out.
__global__ __launch_bounds__(256) void k_compact(const uint4* __restrict__ keys4,
                                                 const SelState* __restrict__ st,
                                                 unsigned int* __restrict__ cand,
                                                 unsigned int* __restrict__ candCnt){
    __shared__ unsigned int buf[2048];
    __shared__ unsigned int lcnt, gbase;
    const unsigned W = st->known;
    if (threadIdx.x == 0) lcnt = 0u;
    __syncthreads();
    const unsigned n4 = TOT/4;
    for (unsigned i = blockIdx.x*256 + threadIdx.x; i < n4; i += gridDim.x*256){
        uint4 v = keys4[i];
        if ((v.x >> 21) == W) buf[atomicAdd(&lcnt,1u)] = v.x;
        if ((v.y >> 21) == W) buf[atomicAdd(&lcnt,1u)] = v.y;
        if ((v.z >> 21) == W) buf[atomicAdd(&lcnt,1u)] = v.z;
        if ((v.w >> 21) == W) buf[atomicAdd(&lcnt,1u)] = v.w;
    }
    __syncthreads();
    if (threadIdx.x == 0 && lcnt > 0u) gbase = atomicAdd(candCnt, lcnt);
    __syncthreads();
    const unsigned n = lcnt;
    for (unsigned j = threadIdx.x; j < n; j += 256) cand[gbase + j] = buf[j];
}

// ---------------- sel2: bitwise binary-search select over candidates (no atomics) ----------------
// All candidates share top-11 bits == st->known. Find the st->rank-th largest 21-bit
// suffix via MSB->LSB bit decisions; counts by register compare + shfl/LDS reduction.
#define SEL2_T 1024
#define SEL2_PER 32          // capacity 32*1024 = 32768 candidates in registers
__global__ __launch_bounds__(SEL2_T) void k_sel2(const unsigned int* __restrict__ cand,
                                                 const unsigned int* __restrict__ candCnt,
                                                 SelState* __restrict__ st){
    __shared__ unsigned int red[SEL2_T/64];
    __shared__ unsigned int shPrefix, shRank;
    const int t = threadIdx.x;
    const unsigned n = *candCnt;
    const bool inreg = (n <= (unsigned)(SEL2_T * SEL2_PER));
    unsigned vals[SEL2_PER];
    if (inreg){
        #pragma unroll
        for (int j = 0; j < SEL2_PER; ++j){
            unsigned i = (unsigned)t + (unsigned)j * SEL2_T;
            vals[j] = (i < n) ? (cand[i] & 0x1FFFFFu) : 0xFFFFFFFFu;  // sentinel never matches
        }
    }
    if (t == 0){ shPrefix = 0u; shRank = st->rank; }
    __syncthreads();
    for (int b = 20; b >= 0; --b){
        const unsigned prefix = shPrefix;
        const unsigned want = (prefix >> b) | 1u;
        unsigned c1 = 0u;
        if (inreg){
            #pragma unroll
            for (int j = 0; j < SEL2_PER; ++j) c1 += ((vals[j] >> b) == want) ? 1u : 0u;
        } else {
            for (unsigned i = t; i < n; i += SEL2_T)
                c1 += (((cand[i] & 0x1FFFFFu) >> b) == want) ? 1u : 0u;
        }
        // wave reduction (64 lanes)
        #pragma unroll
        for (int off = 32; off > 0; off >>= 1) c1 += __shfl_down(c1, off, 64);
        if ((t & 63) == 0) red[t >> 6] = c1;
        __syncthreads();
        if (t == 0){
            unsigned tot = 0u;
            #pragma unroll
            for (int i2 = 0; i2 < SEL2_T/64; ++i2) tot += red[i2];
            if (tot >= shRank) shPrefix = prefix | (1u << b);
            else               shRank  -= tot;
        }
        __syncthreads();
    }
    if (t == 0) st->thrkey = (st->known << 21) | shPrefix;
}

// ---------------- orchestration ----------------
// Freq-domain formulation: G = fft2(X)*T.
//   W = normalize(ifft2(G + Bm_prev)); B = fft2(H*W) - G
//   E = (B*(1-mask) + G)*conj(T); X = thresh(ifft2(E)); G' = fft2(X)*T (fused into rowFA)
// Select: hist1 fused in rowC -> k_scan1 -> k_compact (LDS-staged) -> k_sel2 (binary search).
// ws: t2 16M | B 16M | G 16M | keys 8M | T 4M | tw 8K | hist 8K | st/candCnt | cand 16M
extern "C" void kernel_launch(void* const* d_in, const int* in_sizes, int n_in,
                              void* d_out, int out_size, void* d_ws, size_t ws_size,
                              hipStream_t stream){
    (void)in_sizes; (void)n_in; (void)out_size; (void)ws_size;
    const float2* H = (const float2*)d_in[0];
    const float*  Q = (const float*)d_in[1];
    const float*  zp = (const float*)d_in[2];

    char* ws = (char*)d_ws;
    const size_t A = (size_t)TOT * sizeof(float2);   // 16 MiB
    float2* t2 = (float2*)(ws);
    float2* B  = (float2*)(ws + A);
    float2* G  = (float2*)(ws + 2*A);
    unsigned int* keys = (unsigned int*)(ws + 3*A);              // 8 MiB
    c64* T  = (c64*)(ws + 3*A + (size_t)TOT*4);                  // 4 MiB
    c64* tw = (c64*)(ws + 3*A + (size_t)TOT*4 + (size_t)IMGE*16);
    unsigned int* hist = (unsigned int*)((char*)tw + 512*16);
    SelState* st = (SelState*)((char*)hist + 8192);
    unsigned int* candCnt = (unsigned int*)((char*)hist + 8192 + 64);
    unsigned int* cand = (unsigned int*)(ws + 4*A);              // 16 MiB (4M entries >= TOT)

    float2* outW = (float2*)d_out;
    float2* outB = ((float2*)d_out) + TOT;

    hipMemsetAsync(hist, 0, 8192 + 128, stream);     // hist + st + candCnt
    k_init<<<IMGE/256, 256, 0, stream>>>(Q, zp, T, tw);

    auto sel = [&](){
        k_scan1<<<1,256,0,stream>>>(hist, st, candCnt);
        k_compact<<<1024,256,0,stream>>>((const uint4*)keys, st, cand, candCnt);
        k_sel2<<<1,SEL2_T,0,stream>>>(cand, candCnt, st);
    };

    // ---- iteration 1: X=0 -> G=0, W=1 -> Qc=H ----
    k_colF<<<512,256,0,stream>>>(H, t2, tw);                    // t2 = colF(H)
    k_rowC<true><<<512,256,0,stream>>>(t2, G, B, keys, hist, tw);  // B = fft2(H) [+hist1]
    sel();
    k_rowD<true><<<512,256,0,stream>>>(B, st, G, T, t2, tw);    // E=B(1-m)*conjT, rowI
    k_colX<<<512,256,0,stream>>>(t2, tw);                       // colI -> thresh -> colF

    // ---- iterations 2..5 ----
    for (int iter = 2; iter <= 5; ++iter){
        k_rowFA<<<512,256,0,stream>>>(t2, B, st, T, G, tw);     // G=FX*T; rowI(G+Bm)
        k_colWQ<false><<<512,256,0,stream>>>(t2, H, outW, tw);  // W, Qc, colF(Qc)
        k_rowC<false><<<512,256,0,stream>>>(t2, G, B, keys, hist, tw);
        sel();
        k_rowD<false><<<512,256,0,stream>>>(B, st, G, T, t2, tw);
        k_colX<<<512,256,0,stream>>>(t2, tw);
    }

    // ---- iteration 6: only W and masked B needed ----
    k_rowFA<<<512,256,0,stream>>>(t2, B, st, T, G, tw);
    k_colWQ<true><<<512,256,0,stream>>>(t2, H, outW, tw);       // stores final W
    k_rowC<false><<<512,256,0,stream>>>(t2, G, B, keys, hist, tw);
    sel();
    k_outB<<<TOT/256,256,0,stream>>>(B, keys, st, outB);
}

// Round 16
// 976.303 us; speedup vs baseline: 1.0068x; 1.0068x over previous
//
#include <hip/hip_runtime.h>
#include <math.h>

// Problem constants
#define NIMG 8
#define MDIM 512
#define IMGE (MDIM*MDIM)        // 262144 per image
#define TOT  (NIMG*IMGE)        // 2097152 complex elements
#define BETA_K 4096
#define LAMD 0.1

typedef double2 c64;

struct SelState { unsigned int known; unsigned int rank; unsigned int thrkey; };

// Key derivation — used identically everywhere (rowC store, rowFA/rowD recompute):
// from the ROUNDED f32 components, sqrt in f64, result cast to f32 bits.
__device__ __forceinline__ unsigned int keyOf(float bx, float by){
    return __float_as_uint((float)sqrt((double)bx*(double)bx + (double)by*(double)by));
}

// ---------------- LDS addressing ----------------
// Swizzle XORs bits 1..3 only (bit 0 preserved -> f64 pairs stay ordered-adjacent,
// ds_*_b128 vectorization preserved).
__device__ __forceinline__ int LPOS(int ln, int q){
    return (ln << 9) + (q ^ ((((q >> 4) ^ (2 * ln)) & 7) << 1));
}
__device__ __forceinline__ int rev8(int n){   // base-8 digit reversal of 9-bit index
    return ((n & 7) << 6) | (n & 56) | (n >> 6);
}
__device__ __forceinline__ int rde(int w, int k){ // rev8(8w+k)
    return 64*k + 8*(w & 7) + (w >> 3);
}

// ---------------- 8-point DFT in registers. INV=true: conjugate (inverse) ----------------
template<bool INV>
__device__ __forceinline__ void dft8(double* xr, double* xi){
    const double C = 0.70710678118654752440;
    double t0r=xr[0]+xr[4], t0i=xi[0]+xi[4];
    double t1r=xr[0]-xr[4], t1i=xi[0]-xi[4];
    double t2r=xr[2]+xr[6], t2i=xi[2]+xi[6];
    double t3r=xr[2]-xr[6], t3i=xi[2]-xi[6];
    double m3r = INV ? -t3i : t3i;
    double m3i = INV ?  t3r : -t3r;
    double E0r=t0r+t2r, E0i=t0i+t2i;
    double E2r=t0r-t2r, E2i=t0i-t2i;
    double E1r=t1r+m3r, E1i=t1i+m3i;
    double E3r=t1r-m3r, E3i=t1i-m3i;
    double u0r=xr[1]+xr[5], u0i=xi[1]+xi[5];
    double u1r=xr[1]-xr[5], u1i=xi[1]-xi[5];
    double u2r=xr[3]+xr[7], u2i=xi[3]+xi[7];
    double u3r=xr[3]-xr[7], u3i=xi[3]-xi[7];
    double n3r = INV ? -u3i : u3i;
    double n3i = INV ?  u3r : -u3r;
    double O0r=u0r+u2r, O0i=u0i+u2i;
    double O2r=u0r-u2r, O2i=u0i-u2i;
    double O1r=u1r+n3r, O1i=u1i+n3i;
    double O3r=u1r-n3r, O3i=u1i-n3i;
    double W1r = INV ? C*(O1r - O1i) : C*(O1r + O1i);
    double W1i = INV ? C*(O1r + O1i) : C*(O1i - O1r);
    double W2r = INV ? -O2i : O2i;
    double W2i = INV ?  O2r : -O2r;
    double W3r = INV ? -C*(O3r + O3i) : C*(O3i - O3r);
    double W3i = INV ? C*(O3r - O3i) : -C*(O3r + O3i);
    xr[0]=E0r+O0r; xi[0]=E0i+O0i;  xr[4]=E0r-O0r; xi[4]=E0i-O0i;
    xr[1]=E1r+W1r; xi[1]=E1i+W1i;  xr[5]=E1r-W1r; xi[5]=E1i-W1i;
    xr[2]=E2r+W2r; xi[2]=E2i+W2i;  xr[6]=E2r-W2r; xi[6]=E2i-W2i;
    xr[3]=E3r+W3r; xi[3]=E3i+W3i;  xr[7]=E3r-W3r; xi[7]=E3i-W3i;
}

// ================= ROW-path FFT helpers (register ends) =================
template<bool INV>
__device__ __forceinline__ void dit_from_regs(double (&ar)[2][8], double (&ai)[2][8],
                                              double* re, double* im, const c64* __restrict__ tw){
    const int t=threadIdx.x, w=t&63, l0=t>>6;
    #pragma unroll
    for (int h=0;h<2;++h){
        dft8<INV>(ar[h], ai[h]);
        const int ln=l0+4*h;
        #pragma unroll
        for (int k=0;k<8;++k){ int p=LPOS(ln,8*w+k); re[p]=ar[h][k]; im[p]=ai[h][k]; }
    }
    __syncthreads();
    {   // stage 1: groups 64g+j+8k, twiddle tw[8jk]
        const int g=w>>3, j=w&7;
        double wr[8], wi[8];
        #pragma unroll
        for (int k=1;k<8;++k){ c64 tv=tw[8*j*k]; wr[k]=tv.x; wi[k]=INV?-tv.y:tv.y; }
        #pragma unroll
        for (int h=0;h<2;++h){
            const int ln=l0+4*h;
            double xr[8], xi[8];
            #pragma unroll
            for (int k=0;k<8;++k){ int p=LPOS(ln,64*g+j+8*k); double a=re[p],b=im[p];
                if(k==0){xr[0]=a; xi[0]=b;} else {xr[k]=a*wr[k]-b*wi[k]; xi[k]=a*wi[k]+b*wr[k];} }
            dft8<INV>(xr,xi);
            #pragma unroll
            for (int k=0;k<8;++k){ int p=LPOS(ln,64*g+j+8*k); re[p]=xr[k]; im[p]=xi[k]; }
        }
    }
    __syncthreads();
    {   // stage 2 -> regs: groups j+64k, twiddle tw[jk]
        const int j=w;
        double wr[8], wi[8];
        #pragma unroll
        for (int k=1;k<8;++k){ c64 tv=tw[j*k]; wr[k]=tv.x; wi[k]=INV?-tv.y:tv.y; }
        #pragma unroll
        for (int h=0;h<2;++h){
            const int ln=l0+4*h;
            #pragma unroll
            for (int k=0;k<8;++k){ int p=LPOS(ln,j+64*k); double a=re[p],b=im[p];
                if(k==0){ar[h][0]=a; ai[h][0]=b;} else {ar[h][k]=a*wr[k]-b*wi[k]; ai[h][k]=a*wi[k]+b*wr[k];} }
            dft8<INV>(ar[h], ai[h]);
        }
    }
}

template<bool INV>
__device__ __forceinline__ void dif_to_regs(double (&ar)[2][8], double (&ai)[2][8],
                                            double* re, double* im, const c64* __restrict__ tw){
    const int t=threadIdx.x, w=t&63, l0=t>>6;
    {   // stage A (from regs): dft8, post-twiddle tw[w*k], write at j+64k
        const int j=w;
        double wr[8], wi[8];
        #pragma unroll
        for (int k=1;k<8;++k){ c64 tv=tw[j*k]; wr[k]=tv.x; wi[k]=INV?-tv.y:tv.y; }
        #pragma unroll
        for (int h=0;h<2;++h){
            dft8<INV>(ar[h], ai[h]);
            const int ln=l0+4*h;
            #pragma unroll
            for (int k=0;k<8;++k){
                int p=LPOS(ln,j+64*k);
                if(k==0){ re[p]=ar[h][0]; im[p]=ai[h][0]; }
                else { re[p]=ar[h][k]*wr[k]-ai[h][k]*wi[k]; im[p]=ar[h][k]*wi[k]+ai[h][k]*wr[k]; }
            }
        }
    }
    __syncthreads();
    {   // stage B: groups 64g+j+8k, post-twiddle tw[8jk]
        const int g=w>>3, j=w&7;
        double wr[8], wi[8];
        #pragma unroll
        for (int k=1;k<8;++k){ c64 tv=tw[8*j*k]; wr[k]=tv.x; wi[k]=INV?-tv.y:tv.y; }
        #pragma unroll
        for (int h=0;h<2;++h){
            const int ln=l0+4*h;
            double xr[8], xi[8];
            #pragma unroll
            for (int k=0;k<8;++k){ int p=LPOS(ln,64*g+j+8*k); xr[k]=re[p]; xi[k]=im[p]; }
            dft8<INV>(xr,xi);
            #pragma unroll
            for (int k=0;k<8;++k){
                int p=LPOS(ln,64*g+j+8*k);
                if(k==0){ re[p]=xr[0]; im[p]=xi[0]; }
                else { re[p]=xr[k]*wr[k]-xi[k]*wi[k]; im[p]=xr[k]*wi[k]+xi[k]*wr[k]; }
            }
        }
    }
    __syncthreads();
    // stage C -> regs (no twiddle)
    #pragma unroll
    for (int h=0;h<2;++h){
        const int ln=l0+4*h;
        #pragma unroll
        for (int k=0;k<8;++k){ int p=LPOS(ln,8*w+k); ar[h][k]=re[p]; ai[h][k]=im[p]; }
        dft8<INV>(ar[h], ai[h]);
    }
}

// ================= COL-path FFT (full-LDS) =================
template<bool INV>
__device__ void r8_dit(double* re, double* im, const c64* __restrict__ tw){
    const int t = threadIdx.x;
    const int w = t & 63;
    const int l0 = t >> 6;
    __syncthreads();
    #pragma unroll
    for (int h = 0; h < 2; ++h){
        const int ln = l0 + 4*h;
        double xr[8], xi[8];
        #pragma unroll
        for (int k = 0; k < 8; ++k){ int p = LPOS(ln, 8*w + k); xr[k]=re[p]; xi[k]=im[p]; }
        dft8<INV>(xr, xi);
        #pragma unroll
        for (int k = 0; k < 8; ++k){ int p = LPOS(ln, 8*w + k); re[p]=xr[k]; im[p]=xi[k]; }
    }
    {
        const int g = w >> 3, j = w & 7;
        double wr[8], wi[8];
        #pragma unroll
        for (int k = 1; k < 8; ++k){ c64 tv = tw[8*j*k]; wr[k]=tv.x; wi[k]= INV ? -tv.y : tv.y; }
        __syncthreads();
        #pragma unroll
        for (int h = 0; h < 2; ++h){
            const int ln = l0 + 4*h;
            double xr[8], xi[8];
            #pragma unroll
            for (int k = 0; k < 8; ++k){
                int p = LPOS(ln, 64*g + j + 8*k); double a=re[p], b=im[p];
                if (k == 0){ xr[0]=a; xi[0]=b; }
                else { xr[k]=a*wr[k]-b*wi[k]; xi[k]=a*wi[k]+b*wr[k]; }
            }
            dft8<INV>(xr, xi);
            #pragma unroll
            for (int k = 0; k < 8; ++k){ int p = LPOS(ln, 64*g + j + 8*k); re[p]=xr[k]; im[p]=xi[k]; }
        }
    }
    {
        const int j = w;
        double wr[8], wi[8];
        #pragma unroll
        for (int k = 1; k < 8; ++k){ c64 tv = tw[j*k]; wr[k]=tv.x; wi[k]= INV ? -tv.y : tv.y; }
        __syncthreads();
        #pragma unroll
        for (int h = 0; h < 2; ++h){
            const int ln = l0 + 4*h;
            double xr[8], xi[8];
            #pragma unroll
            for (int k = 0; k < 8; ++k){
                int p = LPOS(ln, j + 64*k); double a=re[p], b=im[p];
                if (k == 0){ xr[0]=a; xi[0]=b; }
                else { xr[k]=a*wr[k]-b*wi[k]; xi[k]=a*wi[k]+b*wr[k]; }
            }
            dft8<INV>(xr, xi);
            #pragma unroll
            for (int k = 0; k < 8; ++k){ int p = LPOS(ln, j + 64*k); re[p]=xr[k]; im[p]=xi[k]; }
        }
    }
}

template<bool INV>
__device__ void r8_dif(double* re, double* im, const c64* __restrict__ tw){
    const int t = threadIdx.x;
    const int w = t & 63;
    const int l0 = t >> 6;
    {
        const int j = w;
        double wr[8], wi[8];
        #pragma unroll
        for (int k = 1; k < 8; ++k){ c64 tv = tw[j*k]; wr[k]=tv.x; wi[k]= INV ? -tv.y : tv.y; }
        __syncthreads();
        #pragma unroll
        for (int h = 0; h < 2; ++h){
            const int ln = l0 + 4*h;
            double xr[8], xi[8];
            #pragma unroll
            for (int k = 0; k < 8; ++k){ int p = LPOS(ln, j + 64*k); xr[k]=re[p]; xi[k]=im[p]; }
            dft8<INV>(xr, xi);
            #pragma unroll
            for (int k = 0; k < 8; ++k){
                int p = LPOS(ln, j + 64*k);
                if (k == 0){ re[p]=xr[0]; im[p]=xi[0]; }
                else { re[p]=xr[k]*wr[k]-xi[k]*wi[k]; im[p]=xr[k]*wi[k]+xi[k]*wr[k]; }
            }
        }
    }
    {
        const int g = w >> 3, j = w & 7;
        double wr[8], wi[8];
        #pragma unroll
        for (int k = 1; k < 8; ++k){ c64 tv = tw[8*j*k]; wr[k]=tv.x; wi[k]= INV ? -tv.y : tv.y; }
        __syncthreads();
        #pragma unroll
        for (int h = 0; h < 2; ++h){
            const int ln = l0 + 4*h;
            double xr[8], xi[8];
            #pragma unroll
            for (int k = 0; k < 8; ++k){ int p = LPOS(ln, 64*g + j + 8*k); xr[k]=re[p]; xi[k]=im[p]; }
            dft8<INV>(xr, xi);
            #pragma unroll
            for (int k = 0; k < 8; ++k){
                int p = LPOS(ln, 64*g + j + 8*k);
                if (k == 0){ re[p]=xr[0]; im[p]=xi[0]; }
                else { re[p]=xr[k]*wr[k]-xi[k]*wi[k]; im[p]=xr[k]*wi[k]+xi[k]*wr[k]; }
            }
        }
    }
    __syncthreads();
    #pragma unroll
    for (int h = 0; h < 2; ++h){
        const int ln = l0 + 4*h;
        double xr[8], xi[8];
        #pragma unroll
        for (int k = 0; k < 8; ++k){ int p = LPOS(ln, 8*w + k); xr[k]=re[p]; xi[k]=im[p]; }
        dft8<INV>(xr, xi);
        #pragma unroll
        for (int k = 0; k < 8; ++k){ int p = LPOS(ln, 8*w + k); re[p]=xr[k]; im[p]=xi[k]; }
    }
}

__device__ __forceinline__ void col_load32(const float2* __restrict__ src, size_t base,
                                           double* re, double* im){
    const int t = threadIdx.x;
    #pragma unroll
    for (int it = 0; it < 16; ++it){
        int idx = it*256 + t; int ln = idx & 7, e = idx >> 3;
        float2 v = src[base + ln + (size_t)e*512];
        int p = LPOS(ln, rev8(e));
        re[p] = (double)v.x; im[p] = (double)v.y;
    }
}

// ---------------- init: T = exp(i*(z/WL)*Q) (f64), twiddles (f64) ----------------
__global__ __launch_bounds__(256) void k_init(const float* __restrict__ Q,
                                              const float* __restrict__ zp,
                                              c64* __restrict__ T,
                                              c64* __restrict__ tw){
    int i = blockIdx.x*256 + threadIdx.x;
    if (i < IMGE){
        double a = ((double)zp[0] / 6.37e-07) * (double)Q[i];
        T[i] = make_double2(cos(a), sin(a));
    }
    if (i < 512){
        double a = -6.283185307179586476925286766559 * ((double)i / 512.0);
        tw[i] = make_double2(cos(a), sin(a));
    }
}

// ---------------- k_colF (iter 1): forward col FFT of H -> t2 ----------------
__global__ __launch_bounds__(256,2) void k_colF(const float2* __restrict__ H,
                                                float2* __restrict__ t2,
                                                const c64* __restrict__ tw){
    __shared__ double re[4096]; __shared__ double im[4096];
    const int t = threadIdx.x, blk = blockIdx.x;
    const size_t base = (size_t)(blk >> 6) * IMGE + (size_t)(blk & 63) * 8;
    col_load32(H, base, re, im);
    r8_dit<false>(re, im, tw);
    __syncthreads();
    #pragma unroll
    for (int it = 0; it < 16; ++it){
        int idx = it*256 + t; int ln = idx & 7, e = idx >> 3;
        int p = LPOS(ln, e);
        t2[base + ln + (size_t)e*512] = make_float2((float)re[p], (float)im[p]);
    }
}

// ---------------- k_rowFA: rowF(X) -> G=FX*T (store); then rowI(G + Bm) -> t2 ----------------
__global__ __launch_bounds__(256,2) void k_rowFA(float2* __restrict__ t2,
                                                 const float2* __restrict__ B,
                                                 const SelState* __restrict__ st,
                                                 const c64* __restrict__ T,
                                                 float2* __restrict__ G,
                                                 const c64* __restrict__ tw){
    __shared__ double re[4096]; __shared__ double im[4096];
    const int t = threadIdx.x, blk = blockIdx.x;
    const int w = t & 63, l0 = t >> 6;
    const size_t base = (size_t)blk * 4096;
    const unsigned int thr = st->thrkey;
    double ar[2][8], ai[2][8];
    #pragma unroll
    for (int h=0;h<2;++h){ const int ln=l0+4*h;
        #pragma unroll
        for (int k=0;k<8;++k){ float2 v = t2[base + ln*512 + rde(w,k)];
            ar[h][k]=(double)v.x; ai[h][k]=(double)v.y; } }
    dit_from_regs<false>(ar, ai, re, im, tw);      // rowF of colF(X): full fft2(X) rows
    #pragma unroll
    for (int h=0;h<2;++h){
        const int ln=l0+4*h;
        const int u = (blk & 63) * 8 + ln;
        #pragma unroll
        for (int k=0;k<8;++k){
            const int e = w + 64*k;
            size_t addr = base + ln*512 + e;
            c64 tv = T[u*512 + e];
            double xr = ar[h][k], xi = ai[h][k];
            double gr = xr*tv.x - xi*tv.y;         // G = fft2(X)*T
            double gi = xr*tv.y + xi*tv.x;
            G[addr] = make_float2((float)gr, (float)gi);
            float2 b = B[addr];
            bool keep = keyOf(b.x, b.y) >= thr;    // Bm = top-k kept (key recomputed)
            ar[h][k] = gr + (keep ? (double)b.x : 0.0);
            ai[h][k] = gi + (keep ? (double)b.y : 0.0);
        }
    }
    dif_to_regs<true>(ar, ai, re, im, tw);         // rowI(G + Bm)
    const double sc = 1.0/512.0;
    #pragma unroll
    for (int h=0;h<2;++h){ const int ln=l0+4*h;
        #pragma unroll
        for (int k=0;k<8;++k)
            t2[base + ln*512 + rde(w,k)] = make_float2((float)(ar[h][k]*sc), (float)(ai[h][k]*sc)); }
}

// ---------------- kB: colI -> W=normalize(Z) -> Qc=H*W -> colF(Qc) ----------------
template<bool FINAL>
__global__ __launch_bounds__(256,2) void k_colWQ(float2* __restrict__ t2,
                                                 const float2* __restrict__ H,
                                                 float2* __restrict__ outW,
                                                 const c64* __restrict__ tw){
    __shared__ double re[4096]; __shared__ double im[4096];
    const int t = threadIdx.x, blk = blockIdx.x;
    const size_t base = (size_t)(blk >> 6) * IMGE + (size_t)(blk & 63) * 8;
    col_load32(t2, base, re, im);
    r8_dit<true>(re, im, tw);          // inverse col FFT (unscaled here)
    __syncthreads();
    const double sc = 1.0/512.0;
    #pragma unroll
    for (int it = 0; it < 16; ++it){
        int idx = it*256 + t; int ln = idx & 7, e = idx >> 3;
        size_t addr = base + ln + (size_t)e*512;
        int p = LPOS(ln, e);
        double zr = re[p]*sc, zi = im[p]*sc;   // Z = convXT + IB (spatial)
        double m = sqrt(zr*zr + zi*zi);
        double d = (m == 0.0) ? 1.0 : m;
        double wx = zr/d, wy = zi/d;           // W = normalize(Z)
        if (FINAL) outW[addr] = make_float2((float)wx, (float)wy);
        float2 h = H[addr];
        re[p] = (double)h.x*wx - (double)h.y*wy;   // Qc = H*W
        im[p] = (double)h.x*wy + (double)h.y*wx;
    }
    r8_dif<false>(re, im, tw);         // forward col FFT of Qc
    __syncthreads();
    #pragma unroll
    for (int it = 0; it < 16; ++it){
        int idx = it*256 + t; int ln = idx & 7, e = idx >> 3;
        int p = LPOS(ln, rev8(e));
        t2[base + ln + (size_t)e*512] = make_float2((float)re[p], (float)im[p]);
    }
}

// ---------------- kC: rowF -> B = FQc - G -> store B/keys + fused hist pass-1 ----------------
template<bool G0>
__global__ __launch_bounds__(256,2) void k_rowC(const float2* __restrict__ t2,
                                                const float2* __restrict__ G,
                                                float2* __restrict__ B,
                                                unsigned int* __restrict__ keys,
                                                unsigned int* __restrict__ hist,
                                                const c64* __restrict__ tw){
    __shared__ double re[4096]; __shared__ double im[4096];
    const int t = threadIdx.x, blk = blockIdx.x;
    const int w = t & 63, l0 = t >> 6;
    const size_t base = (size_t)blk * 4096;
    double ar[2][8], ai[2][8];
    #pragma unroll
    for (int h=0;h<2;++h){ const int ln=l0+4*h;
        #pragma unroll
        for (int k=0;k<8;++k){ float2 v = t2[base + ln*512 + rde(w,k)];
            ar[h][k]=(double)v.x; ai[h][k]=(double)v.y; } }
    dit_from_regs<false>(ar, ai, re, im, tw);
    __syncthreads();                   // stage-2 LDS reads done -> reuse re as hist
    unsigned int* lh = reinterpret_cast<unsigned int*>(re);
    for (int b = t; b < 2048; b += 256) lh[b] = 0u;
    __syncthreads();
    #pragma unroll
    for (int h=0;h<2;++h){
        const int ln=l0+4*h;
        #pragma unroll
        for (int k=0;k<8;++k){
            size_t addr = base + ln*512 + (w + 64*k);
            double br = ar[h][k], bi = ai[h][k];
            if (!G0){ float2 g = G[addr]; br -= (double)g.x; bi -= (double)g.y; }
            float fbr = (float)br, fbi = (float)bi;
            B[addr] = make_float2(fbr, fbi);
            unsigned int key = keyOf(fbr, fbi);    // from ROUNDED f32 (matches consumers)
            keys[addr] = key;
            atomicAdd(&lh[key >> 21], 1u);
        }
    }
    __syncthreads();
    for (int b = t; b < 2048; b += 256){
        unsigned int v = lh[b];
        if (v) atomicAdd(&hist[b], v);
    }
}

// ---------------- kD: E = (B*(1-mask) + G)*conj(T) -> rowI -> t2 (x1/512) ----------------
template<bool G0>
__global__ __launch_bounds__(256,2) void k_rowD(const float2* __restrict__ B,
                                                const SelState* __restrict__ st,
                                                const float2* __restrict__ G,
                                                const c64* __restrict__ T,
                                                float2* __restrict__ t2,
                                                const c64* __restrict__ tw){
    __shared__ double re[4096]; __shared__ double im[4096];
    const int t = threadIdx.x, blk = blockIdx.x;
    const int w = t & 63, l0 = t >> 6;
    const size_t base = (size_t)blk * 4096;
    const unsigned int thr = st->thrkey;
    double ar[2][8], ai[2][8];
    #pragma unroll
    for (int h=0;h<2;++h){
        const int ln=l0+4*h;
        const int u = (blk & 63) * 8 + ln;
        #pragma unroll
        for (int k=0;k<8;++k){
            const int e = w + 64*k;
            size_t addr = base + ln*512 + e;
            float2 b = B[addr];
            bool lo = keyOf(b.x, b.y) < thr;      // complement of top-k mask (key recomputed)
            double vr = lo ? (double)b.x : 0.0;
            double vi = lo ? (double)b.y : 0.0;
            if (!G0){ float2 g = G[addr]; vr += (double)g.x; vi += (double)g.y; }
            c64 tv = T[u*512 + e];
            ar[h][k] = vr*tv.x + vi*tv.y;         // * conj(T)
            ai[h][k] = vi*tv.x - vr*tv.y;
        }
    }
    dif_to_regs<true>(ar, ai, re, im, tw);
    const double sc = 1.0/512.0;
    #pragma unroll
    for (int h=0;h<2;++h){ const int ln=l0+4*h;
        #pragma unroll
        for (int k=0;k<8;++k)
            t2[base + ln*512 + rde(w,k)] = make_float2((float)(ar[h][k]*sc), (float)(ai[h][k]*sc)); }
}

// ---------------- kE: colI -> X = inp1*(|inp1|>LAM) -> colF(X) ----------------
__global__ __launch_bounds__(256,2) void k_colX(float2* __restrict__ t2,
                                                const c64* __restrict__ tw){
    __shared__ double re[4096]; __shared__ double im[4096];
    const int t = threadIdx.x, blk = blockIdx.x;
    const size_t base = (size_t)(blk >> 6) * IMGE + (size_t)(blk & 63) * 8;
    col_load32(t2, base, re, im);
    r8_dit<true>(re, im, tw);
    __syncthreads();
    const double sc = 1.0/512.0;
    #pragma unroll
    for (int it = 0; it < 16; ++it){
        int idx = it*256 + t;
        int p = LPOS(idx & 7, idx >> 3);
        double vr = re[p]*sc, vi = im[p]*sc;      // inp1
        double m = sqrt(vr*vr + vi*vi);
        bool keep = m > LAMD;
        re[p] = keep ? vr : 0.0;
        im[p] = keep ? vi : 0.0;
    }
    r8_dif<false>(re, im, tw);
    __syncthreads();
    #pragma unroll
    for (int it = 0; it < 16; ++it){
        int idx = it*256 + t; int ln = idx & 7, e = idx >> 3;
        int p = LPOS(ln, rev8(e));
        t2[base + ln + (size_t)e*512] = make_float2((float)re[p], (float)im[p]);
    }
}

// ---------------- final masked B -> d_out second half ----------------
__global__ __launch_bounds__(256) void k_outB(const float2* __restrict__ B,
                                              const unsigned int* __restrict__ keys,
                                              const SelState* __restrict__ st,
                                              float2* __restrict__ outB){
    int i = blockIdx.x*256 + threadIdx.x;
    float2 v = B[i];
    if (keys[i] < st->thrkey) v = make_float2(0.0f, 0.0f);
    outB[i] = v;
}

// ---------------- select pass 1 scan (hist from k_rowC); zeroes candCnt ----------------
__global__ __launch_bounds__(256) void k_scan1(unsigned int* __restrict__ hist,
                                               SelState* __restrict__ st,
                                               unsigned int* __restrict__ candCnt){
    __shared__ unsigned int s[256];
    const int t = threadIdx.x;
    unsigned c[8];
    unsigned local = 0u;
    const int b0 = t * 8;
    #pragma unroll
    for (int j = 0; j < 8; ++j){
        unsigned v = hist[b0 + j]; hist[b0 + j] = 0u;
        c[j] = v; local += v;
    }
    if (t == 0) *candCnt = 0u;
    s[t] = local;
    __syncthreads();
    #pragma unroll
    for (int off = 1; off < 256; off <<= 1){
        unsigned add = (t + off < 256) ? s[t + off] : 0u;
        __syncthreads();
        s[t] += add;
        __syncthreads();
    }
    unsigned rank = (unsigned)BETA_K;
    unsigned stot   = s[t];
    unsigned sAfter = (t < 255) ? s[t + 1] : 0u;
    if (sAfter < rank && stot >= rank){
        unsigned cum = sAfter;
        int j = 7;
        #pragma unroll
        for (int k = 7; k >= 0; --k){
            j = k;
            if (cum + c[k] >= rank) break;
            cum += c[k];
        }
        st->rank  = rank - cum;
        st->known = (unsigned)(b0 + j);
    }
}

// ---------------- compact (LDS-staged): keys with top-11 bits == st->known -> cand ----------------
// 1024 blocks x 256 thr, each block covers exactly 2048 keys (512 uint4) -> LDS buf bound 2048.
// LDS atomics for intra-block slots; ONE global atomicAdd per block; coalesced copy-out.
__global__ __launch_bounds__(256) void k_compact(const uint4* __restrict__ keys4,
                                                 const SelState* __restrict__ st,
                                                 unsigned int* __restrict__ cand,
                                                 unsigned int* __restrict__ candCnt){
    __shared__ unsigned int buf[2048];
    __shared__ unsigned int lcnt, gbase;
    const unsigned W = st->known;
    if (threadIdx.x == 0) lcnt = 0u;
    __syncthreads();
    const unsigned n4 = TOT/4;
    for (unsigned i = blockIdx.x*256 + threadIdx.x; i < n4; i += gridDim.x*256){
        uint4 v = keys4[i];
        if ((v.x >> 21) == W) buf[atomicAdd(&lcnt,1u)] = v.x;
        if ((v.y >> 21) == W) buf[atomicAdd(&lcnt,1u)] = v.y;
        if ((v.z >> 21) == W) buf[atomicAdd(&lcnt,1u)] = v.z;
        if ((v.w >> 21) == W) buf[atomicAdd(&lcnt,1u)] = v.w;
    }
    __syncthreads();
    if (threadIdx.x == 0 && lcnt > 0u) gbase = atomicAdd(candCnt, lcnt);
    __syncthreads();
    const unsigned n = lcnt;
    for (unsigned j = threadIdx.x; j < n; j += 256) cand[gbase + j] = buf[j];
}

// ---------------- sel2: bitwise binary-search select over candidates (no atomics) ----------------
// All candidates share top-11 bits == st->known. Find the st->rank-th largest 21-bit
// suffix via MSB->LSB bit decisions. Candidates PINNED in VGPRs via asm keep-alive
// (round-15 failure: compiler sank the loads into the loop -> 21x global re-reads).
#define SEL2_T 1024
#define SEL2_PER 32          // capacity 32*1024 = 32768 candidates in registers
__global__ __launch_bounds__(SEL2_T) void k_sel2(const unsigned int* __restrict__ cand,
                                                 const unsigned int* __restrict__ candCnt,
                                                 SelState* __restrict__ st){
    __shared__ unsigned int red[SEL2_T/64];
    __shared__ unsigned int shPrefix, shRank;
    const int t = threadIdx.x;
    const unsigned n = *candCnt;
    if (t == 0){ shPrefix = 0u; shRank = st->rank; }
    if (n <= (unsigned)(SEL2_T * SEL2_PER)){
        unsigned vals[SEL2_PER];
        #pragma unroll
        for (int j = 0; j < SEL2_PER; ++j){
            unsigned i = (unsigned)t + (unsigned)j * SEL2_T;
            vals[j] = (i < n) ? (cand[i] & 0x1FFFFFu) : 0xFFFFFFFFu;  // sentinel never matches
        }
        // Pin vals into VGPRs: opaque to the optimizer, cannot be rematerialized from memory.
        #pragma unroll
        for (int j = 0; j < SEL2_PER; ++j) asm volatile("" : "+v"(vals[j]));
        __syncthreads();
        for (int b = 20; b >= 0; --b){
            const unsigned prefix = shPrefix;
            const unsigned want = (prefix >> b) | 1u;
            unsigned c1 = 0u;
            #pragma unroll
            for (int j = 0; j < SEL2_PER; ++j) c1 += ((vals[j] >> b) == want) ? 1u : 0u;
            #pragma unroll
            for (int off = 32; off > 0; off >>= 1) c1 += __shfl_down(c1, off, 64);
            if ((t & 63) == 0) red[t >> 6] = c1;
            __syncthreads();
            if (t == 0){
                unsigned tot = 0u;
                #pragma unroll
                for (int i2 = 0; i2 < SEL2_T/64; ++i2) tot += red[i2];
                if (tot >= shRank) shPrefix = prefix | (1u << b);
                else               shRank  -= tot;
            }
            __syncthreads();
        }
        if (t == 0) st->thrkey = (st->known << 21) | shPrefix;
    } else {
        // fallback (n > 32768): stream from global each round
        __syncthreads();
        for (int b = 20; b >= 0; --b){
            const unsigned prefix = shPrefix;
            const unsigned want = (prefix >> b) | 1u;
            unsigned c1 = 0u;
            for (unsigned i = t; i < n; i += SEL2_T)
                c1 += (((cand[i] & 0x1FFFFFu) >> b) == want) ? 1u : 0u;
            #pragma unroll
            for (int off = 32; off > 0; off >>= 1) c1 += __shfl_down(c1, off, 64);
            if ((t & 63) == 0) red[t >> 6] = c1;
            __syncthreads();
            if (t == 0){
                unsigned tot = 0u;
                #pragma unroll
                for (int i2 = 0; i2 < SEL2_T/64; ++i2) tot += red[i2];
                if (tot >= shRank) shPrefix = prefix | (1u << b);
                else               shRank  -= tot;
            }
            __syncthreads();
        }
        if (t == 0) st->thrkey = (st->known << 21) | shPrefix;
    }
}

// ---------------- orchestration ----------------
// Freq-domain formulation: G = fft2(X)*T.
//   W = normalize(ifft2(G + Bm_prev)); B = fft2(H*W) - G
//   E = (B*(1-mask) + G)*conj(T); X = thresh(ifft2(E)); G' = fft2(X)*T (fused into rowFA)
// Select: hist1 fused in rowC -> k_scan1 -> k_compact (LDS-staged) -> k_sel2 (reg binsearch).
// ws: t2 16M | B 16M | G 16M | keys 8M | T 4M | tw 8K | hist 8K | st/candCnt | cand 16M
extern "C" void kernel_launch(void* const* d_in, const int* in_sizes, int n_in,
                              void* d_out, int out_size, void* d_ws, size_t ws_size,
                              hipStream_t stream){
    (void)in_sizes; (void)n_in; (void)out_size; (void)ws_size;
    const float2* H = (const float2*)d_in[0];
    const float*  Q = (const float*)d_in[1];
    const float*  zp = (const float*)d_in[2];

    char* ws = (char*)d_ws;
    const size_t A = (size_t)TOT * sizeof(float2);   // 16 MiB
    float2* t2 = (float2*)(ws);
    float2* B  = (float2*)(ws + A);
    float2* G  = (float2*)(ws + 2*A);
    unsigned int* keys = (unsigned int*)(ws + 3*A);              // 8 MiB
    c64* T  = (c64*)(ws + 3*A + (size_t)TOT*4);                  // 4 MiB
    c64* tw = (c64*)(ws + 3*A + (size_t)TOT*4 + (size_t)IMGE*16);
    unsigned int* hist = (unsigned int*)((char*)tw + 512*16);
    SelState* st = (SelState*)((char*)hist + 8192);
    unsigned int* candCnt = (unsigned int*)((char*)hist + 8192 + 64);
    unsigned int* cand = (unsigned int*)(ws + 4*A);              // 16 MiB (4M entries >= TOT)

    float2* outW = (float2*)d_out;
    float2* outB = ((float2*)d_out) + TOT;

    hipMemsetAsync(hist, 0, 8192 + 128, stream);     // hist + st + candCnt
    k_init<<<IMGE/256, 256, 0, stream>>>(Q, zp, T, tw);

    auto sel = [&](){
        k_scan1<<<1,256,0,stream>>>(hist, st, candCnt);
        k_compact<<<1024,256,0,stream>>>((const uint4*)keys, st, cand, candCnt);
        k_sel2<<<1,SEL2_T,0,stream>>>(cand, candCnt, st);
    };

    // ---- iteration 1: X=0 -> G=0, W=1 -> Qc=H ----
    k_colF<<<512,256,0,stream>>>(H, t2, tw);                    // t2 = colF(H)
    k_rowC<true><<<512,256,0,stream>>>(t2, G, B, keys, hist, tw);  // B = fft2(H) [+hist1]
    sel();
    k_rowD<true><<<512,256,0,stream>>>(B, st, G, T, t2, tw);    // E=B(1-m)*conjT, rowI
    k_colX<<<512,256,0,stream>>>(t2, tw);                       // colI -> thresh -> colF

    // ---- iterations 2..5 ----
    for (int iter = 2; iter <= 5; ++iter){
        k_rowFA<<<512,256,0,stream>>>(t2, B, st, T, G, tw);     // G=FX*T; rowI(G+Bm)
        k_colWQ<false><<<512,256,0,stream>>>(t2, H, outW, tw);  // W, Qc, colF(Qc)
        k_rowC<false><<<512,256,0,stream>>>(t2, G, B, keys, hist, tw);
        sel();
        k_rowD<false><<<512,256,0,stream>>>(B, st, G, T, t2, tw);
        k_colX<<<512,256,0,stream>>>(t2, tw);
    }

    // ---- iteration 6: only W and masked B needed ----
    k_rowFA<<<512,256,0,stream>>>(t2, B, st, T, G, tw);
    k_colWQ<true><<<512,256,0,stream>>>(t2, H, outW, tw);       // stores final W
    k_rowC<false><<<512,256,0,stream>>>(t2, G, B, keys, hist, tw);
    sel();
    k_outB<<<TOT/256,256,0,stream>>>(B, keys, st, outB);
}

// Round 17
// 730.053 us; speedup vs baseline: 1.3464x; 1.3373x over previous
//
#include <hip/hip_runtime.h>
#include <math.h>

// Problem constants
#define NIMG 8
#define MDIM 512
#define IMGE (MDIM*MDIM)        // 262144 per image
#define TOT  (NIMG*IMGE)        // 2097152 complex elements
#define BETA_K 4096
#define LAMD 0.1

typedef double2 c64;

struct SelState { unsigned int known; unsigned int rank; unsigned int thrkey; };

// Key derivation — used identically everywhere (rowC store, rowFA/rowD recompute):
// from the ROUNDED f32 components, sqrt in f64, result cast to f32 bits.
__device__ __forceinline__ unsigned int keyOf(float bx, float by){
    return __float_as_uint((float)sqrt((double)bx*(double)bx + (double)by*(double)by));
}

// ---------------- LDS addressing ----------------
// Swizzle XORs bits 1..3 only (bit 0 preserved -> f64 pairs stay ordered-adjacent,
// ds_*_b128 vectorization preserved).
__device__ __forceinline__ int LPOS(int ln, int q){
    return (ln << 9) + (q ^ ((((q >> 4) ^ (2 * ln)) & 7) << 1));
}
__device__ __forceinline__ int rev8(int n){   // base-8 digit reversal of 9-bit index
    return ((n & 7) << 6) | (n & 56) | (n >> 6);
}
__device__ __forceinline__ int rde(int w, int k){ // rev8(8w+k)
    return 64*k + 8*(w & 7) + (w >> 3);
}

// ---------------- 8-point DFT in registers. INV=true: conjugate (inverse) ----------------
template<bool INV>
__device__ __forceinline__ void dft8(double* xr, double* xi){
    const double C = 0.70710678118654752440;
    double t0r=xr[0]+xr[4], t0i=xi[0]+xi[4];
    double t1r=xr[0]-xr[4], t1i=xi[0]-xi[4];
    double t2r=xr[2]+xr[6], t2i=xi[2]+xi[6];
    double t3r=xr[2]-xr[6], t3i=xi[2]-xi[6];
    double m3r = INV ? -t3i : t3i;
    double m3i = INV ?  t3r : -t3r;
    double E0r=t0r+t2r, E0i=t0i+t2i;
    double E2r=t0r-t2r, E2i=t0i-t2i;
    double E1r=t1r+m3r, E1i=t1i+m3i;
    double E3r=t1r-m3r, E3i=t1i-m3i;
    double u0r=xr[1]+xr[5], u0i=xi[1]+xi[5];
    double u1r=xr[1]-xr[5], u1i=xi[1]-xi[5];
    double u2r=xr[3]+xr[7], u2i=xi[3]+xi[7];
    double u3r=xr[3]-xr[7], u3i=xi[3]-xi[7];
    double n3r = INV ? -u3i : u3i;
    double n3i = INV ?  u3r : -u3r;
    double O0r=u0r+u2r, O0i=u0i+u2i;
    double O2r=u0r-u2r, O2i=u0i-u2i;
    double O1r=u1r+n3r, O1i=u1i+n3i;
    double O3r=u1r-n3r, O3i=u1i-n3i;
    double W1r = INV ? C*(O1r - O1i) : C*(O1r + O1i);
    double W1i = INV ? C*(O1r + O1i) : C*(O1i - O1r);
    double W2r = INV ? -O2i : O2i;
    double W2i = INV ?  O2r : -O2r;
    double W3r = INV ? -C*(O3r + O3i) : C*(O3i - O3r);
    double W3i = INV ? C*(O3r - O3i) : -C*(O3r + O3i);
    xr[0]=E0r+O0r; xi[0]=E0i+O0i;  xr[4]=E0r-O0r; xi[4]=E0i-O0i;
    xr[1]=E1r+W1r; xi[1]=E1i+W1i;  xr[5]=E1r-W1r; xi[5]=E1i-W1i;
    xr[2]=E2r+W2r; xi[2]=E2i+W2i;  xr[6]=E2r-W2r; xi[6]=E2i-W2i;
    xr[3]=E3r+W3r; xi[3]=E3i+W3i;  xr[7]=E3r-W3r; xi[7]=E3i-W3i;
}

// ================= ROW-path FFT helpers (register ends) =================
template<bool INV>
__device__ __forceinline__ void dit_from_regs(double (&ar)[2][8], double (&ai)[2][8],
                                              double* re, double* im, const c64* __restrict__ tw){
    const int t=threadIdx.x, w=t&63, l0=t>>6;
    #pragma unroll
    for (int h=0;h<2;++h){
        dft8<INV>(ar[h], ai[h]);
        const int ln=l0+4*h;
        #pragma unroll
        for (int k=0;k<8;++k){ int p=LPOS(ln,8*w+k); re[p]=ar[h][k]; im[p]=ai[h][k]; }
    }
    __syncthreads();
    {   // stage 1: groups 64g+j+8k, twiddle tw[8jk]
        const int g=w>>3, j=w&7;
        double wr[8], wi[8];
        #pragma unroll
        for (int k=1;k<8;++k){ c64 tv=tw[8*j*k]; wr[k]=tv.x; wi[k]=INV?-tv.y:tv.y; }
        #pragma unroll
        for (int h=0;h<2;++h){
            const int ln=l0+4*h;
            double xr[8], xi[8];
            #pragma unroll
            for (int k=0;k<8;++k){ int p=LPOS(ln,64*g+j+8*k); double a=re[p],b=im[p];
                if(k==0){xr[0]=a; xi[0]=b;} else {xr[k]=a*wr[k]-b*wi[k]; xi[k]=a*wi[k]+b*wr[k];} }
            dft8<INV>(xr,xi);
            #pragma unroll
            for (int k=0;k<8;++k){ int p=LPOS(ln,64*g+j+8*k); re[p]=xr[k]; im[p]=xi[k]; }
        }
    }
    __syncthreads();
    {   // stage 2 -> regs: groups j+64k, twiddle tw[jk]
        const int j=w;
        double wr[8], wi[8];
        #pragma unroll
        for (int k=1;k<8;++k){ c64 tv=tw[j*k]; wr[k]=tv.x; wi[k]=INV?-tv.y:tv.y; }
        #pragma unroll
        for (int h=0;h<2;++h){
            const int ln=l0+4*h;
            #pragma unroll
            for (int k=0;k<8;++k){ int p=LPOS(ln,j+64*k); double a=re[p],b=im[p];
                if(k==0){ar[h][0]=a; ai[h][0]=b;} else {ar[h][k]=a*wr[k]-b*wi[k]; ai[h][k]=a*wi[k]+b*wr[k];} }
            dft8<INV>(ar[h], ai[h]);
        }
    }
}

template<bool INV>
__device__ __forceinline__ void dif_to_regs(double (&ar)[2][8], double (&ai)[2][8],
                                            double* re, double* im, const c64* __restrict__ tw){
    const int t=threadIdx.x, w=t&63, l0=t>>6;
    {   // stage A (from regs): dft8, post-twiddle tw[w*k], write at j+64k
        const int j=w;
        double wr[8], wi[8];
        #pragma unroll
        for (int k=1;k<8;++k){ c64 tv=tw[j*k]; wr[k]=tv.x; wi[k]=INV?-tv.y:tv.y; }
        #pragma unroll
        for (int h=0;h<2;++h){
            dft8<INV>(ar[h], ai[h]);
            const int ln=l0+4*h;
            #pragma unroll
            for (int k=0;k<8;++k){
                int p=LPOS(ln,j+64*k);
                if(k==0){ re[p]=ar[h][0]; im[p]=ai[h][0]; }
                else { re[p]=ar[h][k]*wr[k]-ai[h][k]*wi[k]; im[p]=ar[h][k]*wi[k]+ai[h][k]*wr[k]; }
            }
        }
    }
    __syncthreads();
    {   // stage B: groups 64g+j+8k, post-twiddle tw[8jk]
        const int g=w>>3, j=w&7;
        double wr[8], wi[8];
        #pragma unroll
        for (int k=1;k<8;++k){ c64 tv=tw[8*j*k]; wr[k]=tv.x; wi[k]=INV?-tv.y:tv.y; }
        #pragma unroll
        for (int h=0;h<2;++h){
            const int ln=l0+4*h;
            double xr[8], xi[8];
            #pragma unroll
            for (int k=0;k<8;++k){ int p=LPOS(ln,64*g+j+8*k); xr[k]=re[p]; xi[k]=im[p]; }
            dft8<INV>(xr,xi);
            #pragma unroll
            for (int k=0;k<8;++k){
                int p=LPOS(ln,64*g+j+8*k);
                if(k==0){ re[p]=xr[0]; im[p]=xi[0]; }
                else { re[p]=xr[k]*wr[k]-xi[k]*wi[k]; im[p]=xr[k]*wi[k]+xi[k]*wr[k]; }
            }
        }
    }
    __syncthreads();
    // stage C -> regs (no twiddle)
    #pragma unroll
    for (int h=0;h<2;++h){
        const int ln=l0+4*h;
        #pragma unroll
        for (int k=0;k<8;++k){ int p=LPOS(ln,8*w+k); ar[h][k]=re[p]; ai[h][k]=im[p]; }
        dft8<INV>(ar[h], ai[h]);
    }
}

// ================= COL-path FFT (full-LDS) =================
template<bool INV>
__device__ void r8_dit(double* re, double* im, const c64* __restrict__ tw){
    const int t = threadIdx.x;
    const int w = t & 63;
    const int l0 = t >> 6;
    __syncthreads();
    #pragma unroll
    for (int h = 0; h < 2; ++h){
        const int ln = l0 + 4*h;
        double xr[8], xi[8];
        #pragma unroll
        for (int k = 0; k < 8; ++k){ int p = LPOS(ln, 8*w + k); xr[k]=re[p]; xi[k]=im[p]; }
        dft8<INV>(xr, xi);
        #pragma unroll
        for (int k = 0; k < 8; ++k){ int p = LPOS(ln, 8*w + k); re[p]=xr[k]; im[p]=xi[k]; }
    }
    {
        const int g = w >> 3, j = w & 7;
        double wr[8], wi[8];
        #pragma unroll
        for (int k = 1; k < 8; ++k){ c64 tv = tw[8*j*k]; wr[k]=tv.x; wi[k]= INV ? -tv.y : tv.y; }
        __syncthreads();
        #pragma unroll
        for (int h = 0; h < 2; ++h){
            const int ln = l0 + 4*h;
            double xr[8], xi[8];
            #pragma unroll
            for (int k = 0; k < 8; ++k){
                int p = LPOS(ln, 64*g + j + 8*k); double a=re[p], b=im[p];
                if (k == 0){ xr[0]=a; xi[0]=b; }
                else { xr[k]=a*wr[k]-b*wi[k]; xi[k]=a*wi[k]+b*wr[k]; }
            }
            dft8<INV>(xr, xi);
            #pragma unroll
            for (int k = 0; k < 8; ++k){ int p = LPOS(ln, 64*g + j + 8*k); re[p]=xr[k]; im[p]=xi[k]; }
        }
    }
    {
        const int j = w;
        double wr[8], wi[8];
        #pragma unroll
        for (int k = 1; k < 8; ++k){ c64 tv = tw[j*k]; wr[k]=tv.x; wi[k]= INV ? -tv.y : tv.y; }
        __syncthreads();
        #pragma unroll
        for (int h = 0; h < 2; ++h){
            const int ln = l0 + 4*h;
            double xr[8], xi[8];
            #pragma unroll
            for (int k = 0; k < 8; ++k){
                int p = LPOS(ln, j + 64*k); double a=re[p], b=im[p];
                if (k == 0){ xr[0]=a; xi[0]=b; }
                else { xr[k]=a*wr[k]-b*wi[k]; xi[k]=a*wi[k]+b*wr[k]; }
            }
            dft8<INV>(xr, xi);
            #pragma unroll
            for (int k = 0; k < 8; ++k){ int p = LPOS(ln, j + 64*k); re[p]=xr[k]; im[p]=xi[k]; }
        }
    }
}

template<bool INV>
__device__ void r8_dif(double* re, double* im, const c64* __restrict__ tw){
    const int t = threadIdx.x;
    const int w = t & 63;
    const int l0 = t >> 6;
    {
        const int j = w;
        double wr[8], wi[8];
        #pragma unroll
        for (int k = 1; k < 8; ++k){ c64 tv = tw[j*k]; wr[k]=tv.x; wi[k]= INV ? -tv.y : tv.y; }
        __syncthreads();
        #pragma unroll
        for (int h = 0; h < 2; ++h){
            const int ln = l0 + 4*h;
            double xr[8], xi[8];
            #pragma unroll
            for (int k = 0; k < 8; ++k){ int p = LPOS(ln, j + 64*k); xr[k]=re[p]; xi[k]=im[p]; }
            dft8<INV>(xr, xi);
            #pragma unroll
            for (int k = 0; k < 8; ++k){
                int p = LPOS(ln, j + 64*k);
                if (k == 0){ re[p]=xr[0]; im[p]=xi[0]; }
                else { re[p]=xr[k]*wr[k]-xi[k]*wi[k]; im[p]=xr[k]*wi[k]+xi[k]*wr[k]; }
            }
        }
    }
    {
        const int g = w >> 3, j = w & 7;
        double wr[8], wi[8];
        #pragma unroll
        for (int k = 1; k < 8; ++k){ c64 tv = tw[8*j*k]; wr[k]=tv.x; wi[k]= INV ? -tv.y : tv.y; }
        __syncthreads();
        #pragma unroll
        for (int h = 0; h < 2; ++h){
            const int ln = l0 + 4*h;
            double xr[8], xi[8];
            #pragma unroll
            for (int k = 0; k < 8; ++k){ int p = LPOS(ln, 64*g + j + 8*k); xr[k]=re[p]; xi[k]=im[p]; }
            dft8<INV>(xr, xi);
            #pragma unroll
            for (int k = 0; k < 8; ++k){
                int p = LPOS(ln, 64*g + j + 8*k);
                if (k == 0){ re[p]=xr[0]; im[p]=xi[0]; }
                else { re[p]=xr[k]*wr[k]-xi[k]*wi[k]; im[p]=xr[k]*wi[k]+xi[k]*wr[k]; }
            }
        }
    }
    __syncthreads();
    #pragma unroll
    for (int h = 0; h < 2; ++h){
        const int ln = l0 + 4*h;
        double xr[8], xi[8];
        #pragma unroll
        for (int k = 0; k < 8; ++k){ int p = LPOS(ln, 8*w + k); xr[k]=re[p]; xi[k]=im[p]; }
        dft8<INV>(xr, xi);
        #pragma unroll
        for (int k = 0; k < 8; ++k){ int p = LPOS(ln, 8*w + k); re[p]=xr[k]; im[p]=xi[k]; }
    }
}

__device__ __forceinline__ void col_load32(const float2* __restrict__ src, size_t base,
                                           double* re, double* im){
    const int t = threadIdx.x;
    #pragma unroll
    for (int it = 0; it < 16; ++it){
        int idx = it*256 + t; int ln = idx & 7, e = idx >> 3;
        float2 v = src[base + ln + (size_t)e*512];
        int p = LPOS(ln, rev8(e));
        re[p] = (double)v.x; im[p] = (double)v.y;
    }
}

// ---------------- init: T = exp(i*(z/WL)*Q) (f64), twiddles (f64) ----------------
__global__ __launch_bounds__(256) void k_init(const float* __restrict__ Q,
                                              const float* __restrict__ zp,
                                              c64* __restrict__ T,
                                              c64* __restrict__ tw){
    int i = blockIdx.x*256 + threadIdx.x;
    if (i < IMGE){
        double a = ((double)zp[0] / 6.37e-07) * (double)Q[i];
        T[i] = make_double2(cos(a), sin(a));
    }
    if (i < 512){
        double a = -6.283185307179586476925286766559 * ((double)i / 512.0);
        tw[i] = make_double2(cos(a), sin(a));
    }
}

// ---------------- k_colF (iter 1): forward col FFT of H -> t2 ----------------
__global__ __launch_bounds__(256,2) void k_colF(const float2* __restrict__ H,
                                                float2* __restrict__ t2,
                                                const c64* __restrict__ tw){
    __shared__ double re[4096]; __shared__ double im[4096];
    const int t = threadIdx.x, blk = blockIdx.x;
    const size_t base = (size_t)(blk >> 6) * IMGE + (size_t)(blk & 63) * 8;
    col_load32(H, base, re, im);
    r8_dit<false>(re, im, tw);
    __syncthreads();
    #pragma unroll
    for (int it = 0; it < 16; ++it){
        int idx = it*256 + t; int ln = idx & 7, e = idx >> 3;
        int p = LPOS(ln, e);
        t2[base + ln + (size_t)e*512] = make_float2((float)re[p], (float)im[p]);
    }
}

// ---------------- k_rowFA: rowF(X) -> G=FX*T (store); then rowI(G + Bm) -> t2 ----------------
__global__ __launch_bounds__(256,2) void k_rowFA(float2* __restrict__ t2,
                                                 const float2* __restrict__ B,
                                                 const SelState* __restrict__ st,
                                                 const c64* __restrict__ T,
                                                 float2* __restrict__ G,
                                                 const c64* __restrict__ tw){
    __shared__ double re[4096]; __shared__ double im[4096];
    const int t = threadIdx.x, blk = blockIdx.x;
    const int w = t & 63, l0 = t >> 6;
    const size_t base = (size_t)blk * 4096;
    const unsigned int thr = st->thrkey;
    double ar[2][8], ai[2][8];
    #pragma unroll
    for (int h=0;h<2;++h){ const int ln=l0+4*h;
        #pragma unroll
        for (int k=0;k<8;++k){ float2 v = t2[base + ln*512 + rde(w,k)];
            ar[h][k]=(double)v.x; ai[h][k]=(double)v.y; } }
    dit_from_regs<false>(ar, ai, re, im, tw);      // rowF of colF(X): full fft2(X) rows
    #pragma unroll
    for (int h=0;h<2;++h){
        const int ln=l0+4*h;
        const int u = (blk & 63) * 8 + ln;
        #pragma unroll
        for (int k=0;k<8;++k){
            const int e = w + 64*k;
            size_t addr = base + ln*512 + e;
            c64 tv = T[u*512 + e];
            double xr = ar[h][k], xi = ai[h][k];
            double gr = xr*tv.x - xi*tv.y;         // G = fft2(X)*T
            double gi = xr*tv.y + xi*tv.x;
            G[addr] = make_float2((float)gr, (float)gi);
            float2 b = B[addr];
            bool keep = keyOf(b.x, b.y) >= thr;    // Bm = top-k kept (key recomputed)
            ar[h][k] = gr + (keep ? (double)b.x : 0.0);
            ai[h][k] = gi + (keep ? (double)b.y : 0.0);
        }
    }
    dif_to_regs<true>(ar, ai, re, im, tw);         // rowI(G + Bm)
    const double sc = 1.0/512.0;
    #pragma unroll
    for (int h=0;h<2;++h){ const int ln=l0+4*h;
        #pragma unroll
        for (int k=0;k<8;++k)
            t2[base + ln*512 + rde(w,k)] = make_float2((float)(ar[h][k]*sc), (float)(ai[h][k]*sc)); }
}

// ---------------- kB: colI -> W=normalize(Z) -> Qc=H*W -> colF(Qc) ----------------
template<bool FINAL>
__global__ __launch_bounds__(256,2) void k_colWQ(float2* __restrict__ t2,
                                                 const float2* __restrict__ H,
                                                 float2* __restrict__ outW,
                                                 const c64* __restrict__ tw){
    __shared__ double re[4096]; __shared__ double im[4096];
    const int t = threadIdx.x, blk = blockIdx.x;
    const size_t base = (size_t)(blk >> 6) * IMGE + (size_t)(blk & 63) * 8;
    col_load32(t2, base, re, im);
    r8_dit<true>(re, im, tw);          // inverse col FFT (unscaled here)
    __syncthreads();
    const double sc = 1.0/512.0;
    #pragma unroll
    for (int it = 0; it < 16; ++it){
        int idx = it*256 + t; int ln = idx & 7, e = idx >> 3;
        size_t addr = base + ln + (size_t)e*512;
        int p = LPOS(ln, e);
        double zr = re[p]*sc, zi = im[p]*sc;   // Z = convXT + IB (spatial)
        double m = sqrt(zr*zr + zi*zi);
        double d = (m == 0.0) ? 1.0 : m;
        double wx = zr/d, wy = zi/d;           // W = normalize(Z)
        if (FINAL) outW[addr] = make_float2((float)wx, (float)wy);
        float2 h = H[addr];
        re[p] = (double)h.x*wx - (double)h.y*wy;   // Qc = H*W
        im[p] = (double)h.x*wy + (double)h.y*wx;
    }
    r8_dif<false>(re, im, tw);         // forward col FFT of Qc
    __syncthreads();
    #pragma unroll
    for (int it = 0; it < 16; ++it){
        int idx = it*256 + t; int ln = idx & 7, e = idx >> 3;
        int p = LPOS(ln, rev8(e));
        t2[base + ln + (size_t)e*512] = make_float2((float)re[p], (float)im[p]);
    }
}

// ---------------- kC: rowF -> B = FQc - G -> store B/keys + fused hist pass-1 ----------------
template<bool G0>
__global__ __launch_bounds__(256,2) void k_rowC(const float2* __restrict__ t2,
                                                const float2* __restrict__ G,
                                                float2* __restrict__ B,
                                                unsigned int* __restrict__ keys,
                                                unsigned int* __restrict__ hist,
                                                const c64* __restrict__ tw){
    __shared__ double re[4096]; __shared__ double im[4096];
    const int t = threadIdx.x, blk = blockIdx.x;
    const int w = t & 63, l0 = t >> 6;
    const size_t base = (size_t)blk * 4096;
    double ar[2][8], ai[2][8];
    #pragma unroll
    for (int h=0;h<2;++h){ const int ln=l0+4*h;
        #pragma unroll
        for (int k=0;k<8;++k){ float2 v = t2[base + ln*512 + rde(w,k)];
            ar[h][k]=(double)v.x; ai[h][k]=(double)v.y; } }
    dit_from_regs<false>(ar, ai, re, im, tw);
    __syncthreads();                   // stage-2 LDS reads done -> reuse re as hist
    unsigned int* lh = reinterpret_cast<unsigned int*>(re);
    for (int b = t; b < 2048; b += 256) lh[b] = 0u;
    __syncthreads();
    #pragma unroll
    for (int h=0;h<2;++h){
        const int ln=l0+4*h;
        #pragma unroll
        for (int k=0;k<8;++k){
            size_t addr = base + ln*512 + (w + 64*k);
            double br = ar[h][k], bi = ai[h][k];
            if (!G0){ float2 g = G[addr]; br -= (double)g.x; bi -= (double)g.y; }
            float fbr = (float)br, fbi = (float)bi;
            B[addr] = make_float2(fbr, fbi);
            unsigned int key = keyOf(fbr, fbi);    // from ROUNDED f32 (matches consumers)
            keys[addr] = key;
            atomicAdd(&lh[key >> 21], 1u);
        }
    }
    __syncthreads();
    for (int b = t; b < 2048; b += 256){
        unsigned int v = lh[b];
        if (v) atomicAdd(&hist[b], v);
    }
}

// ---------------- kD: E = (B*(1-mask) + G)*conj(T) -> rowI -> t2 (x1/512) ----------------
template<bool G0>
__global__ __launch_bounds__(256,2) void k_rowD(const float2* __restrict__ B,
                                                const SelState* __restrict__ st,
                                                const float2* __restrict__ G,
                                                const c64* __restrict__ T,
                                                float2* __restrict__ t2,
                                                const c64* __restrict__ tw){
    __shared__ double re[4096]; __shared__ double im[4096];
    const int t = threadIdx.x, blk = blockIdx.x;
    const int w = t & 63, l0 = t >> 6;
    const size_t base = (size_t)blk * 4096;
    const unsigned int thr = st->thrkey;
    double ar[2][8], ai[2][8];
    #pragma unroll
    for (int h=0;h<2;++h){
        const int ln=l0+4*h;
        const int u = (blk & 63) * 8 + ln;
        #pragma unroll
        for (int k=0;k<8;++k){
            const int e = w + 64*k;
            size_t addr = base + ln*512 + e;
            float2 b = B[addr];
            bool lo = keyOf(b.x, b.y) < thr;      // complement of top-k mask (key recomputed)
            double vr = lo ? (double)b.x : 0.0;
            double vi = lo ? (double)b.y : 0.0;
            if (!G0){ float2 g = G[addr]; vr += (double)g.x; vi += (double)g.y; }
            c64 tv = T[u*512 + e];
            ar[h][k] = vr*tv.x + vi*tv.y;         // * conj(T)
            ai[h][k] = vi*tv.x - vr*tv.y;
        }
    }
    dif_to_regs<true>(ar, ai, re, im, tw);
    const double sc = 1.0/512.0;
    #pragma unroll
    for (int h=0;h<2;++h){ const int ln=l0+4*h;
        #pragma unroll
        for (int k=0;k<8;++k)
            t2[base + ln*512 + rde(w,k)] = make_float2((float)(ar[h][k]*sc), (float)(ai[h][k]*sc)); }
}

// ---------------- kE: colI -> X = inp1*(|inp1|>LAM) -> colF(X) ----------------
__global__ __launch_bounds__(256,2) void k_colX(float2* __restrict__ t2,
                                                const c64* __restrict__ tw){
    __shared__ double re[4096]; __shared__ double im[4096];
    const int t = threadIdx.x, blk = blockIdx.x;
    const size_t base = (size_t)(blk >> 6) * IMGE + (size_t)(blk & 63) * 8;
    col_load32(t2, base, re, im);
    r8_dit<true>(re, im, tw);
    __syncthreads();
    const double sc = 1.0/512.0;
    #pragma unroll
    for (int it = 0; it < 16; ++it){
        int idx = it*256 + t;
        int p = LPOS(idx & 7, idx >> 3);
        double vr = re[p]*sc, vi = im[p]*sc;      // inp1
        double m = sqrt(vr*vr + vi*vi);
        bool keep = m > LAMD;
        re[p] = keep ? vr : 0.0;
        im[p] = keep ? vi : 0.0;
    }
    r8_dif<false>(re, im, tw);
    __syncthreads();
    #pragma unroll
    for (int it = 0; it < 16; ++it){
        int idx = it*256 + t; int ln = idx & 7, e = idx >> 3;
        int p = LPOS(ln, rev8(e));
        t2[base + ln + (size_t)e*512] = make_float2((float)re[p], (float)im[p]);
    }
}

// ---------------- final masked B -> d_out second half ----------------
__global__ __launch_bounds__(256) void k_outB(const float2* __restrict__ B,
                                              const unsigned int* __restrict__ keys,
                                              const SelState* __restrict__ st,
                                              float2* __restrict__ outB){
    int i = blockIdx.x*256 + threadIdx.x;
    float2 v = B[i];
    if (keys[i] < st->thrkey) v = make_float2(0.0f, 0.0f);
    outB[i] = v;
}

// ---------------- radix select: filtered histogram (uint4 reads) + parallel scan ----------------
__global__ __launch_bounds__(256) void k_hist(const uint4* __restrict__ keys4,
                                              unsigned int* __restrict__ hist,
                                              const SelState* __restrict__ st,
                                              int shiftHi, int shift, int dbits){
    __shared__ unsigned int lh[2048];
    int t = threadIdx.x;
    int nd = 1 << dbits;
    for (int b = t; b < nd; b += 256) lh[b] = 0u;
    __syncthreads();
    unsigned known = st->known;
    unsigned msk = (unsigned)((1u << dbits) - 1u);
    const unsigned n4 = TOT/4;
    for (unsigned i = blockIdx.x*256 + t; i < n4; i += gridDim.x*256){
        uint4 v = keys4[i];
        if ((v.x >> shiftHi) == known) atomicAdd(&lh[(v.x >> shift) & msk], 1u);
        if ((v.y >> shiftHi) == known) atomicAdd(&lh[(v.y >> shift) & msk], 1u);
        if ((v.z >> shiftHi) == known) atomicAdd(&lh[(v.z >> shift) & msk], 1u);
        if ((v.w >> shiftHi) == known) atomicAdd(&lh[(v.w >> shift) & msk], 1u);
    }
    __syncthreads();
    for (int b = t; b < nd; b += 256){
        unsigned v = lh[b];
        if (v) atomicAdd(&hist[b], v);
    }
}

// mode: 2=first pass (rank=BETA, known=0), 0=middle, 1=last (writes thrkey).
__global__ __launch_bounds__(256) void k_scan(unsigned int* __restrict__ hist,
                                              SelState* __restrict__ st,
                                              int dbits, int mode){
    __shared__ unsigned int s[256];
    const int t = threadIdx.x;
    const int nd = 1 << dbits;
    const int per = nd >> 8;
    unsigned c[8];
    unsigned local = 0u;
    const int b0 = t * per;
    #pragma unroll
    for (int j = 0; j < 8; ++j){
        unsigned v = 0u;
        if (j < per){ v = hist[b0 + j]; hist[b0 + j] = 0u; }
        c[j] = v; local += v;
    }
    unsigned rank = (mode == 2) ? (unsigned)BETA_K : st->rank;
    s[t] = local;
    __syncthreads();
    #pragma unroll
    for (int off = 1; off < 256; off <<= 1){
        unsigned add = (t + off < 256) ? s[t + off] : 0u;
        __syncthreads();
        s[t] += add;
        __syncthreads();
    }
    unsigned stot   = s[t];
    unsigned sAfter = (t < 255) ? s[t + 1] : 0u;
    if (sAfter < rank && stot >= rank){
        unsigned cum = sAfter;
        int j = per - 1;
        #pragma unroll
        for (int k = 7; k >= 0; --k){
            if (k > per - 1) continue;
            j = k;
            if (cum + c[k] >= rank) break;
            cum += c[k];
        }
        st->rank = rank - cum;
        unsigned kn = (mode == 2) ? 0u : st->known;
        unsigned nk = (kn << dbits) | (unsigned)(b0 + j);
        st->known = nk;
        if (mode == 1) st->thrkey = nk;
    }
}

// ---------------- orchestration ----------------
// Freq-domain formulation: G = fft2(X)*T.
//   W = normalize(ifft2(G + Bm_prev)); B = fft2(H*W) - G
//   E = (B*(1-mask) + G)*conj(T); X = thresh(ifft2(E)); G' = fft2(X)*T (fused into rowFA)
// ws (f32 arrays, f64 tables): t2 16M | B 16M | G 16M | keys 8M | T 4M | tw | hist | st
extern "C" void kernel_launch(void* const* d_in, const int* in_sizes, int n_in,
                              void* d_out, int out_size, void* d_ws, size_t ws_size,
                              hipStream_t stream){
    (void)in_sizes; (void)n_in; (void)out_size; (void)ws_size;
    const float2* H = (const float2*)d_in[0];
    const float*  Q = (const float*)d_in[1];
    const float*  zp = (const float*)d_in[2];

    char* ws = (char*)d_ws;
    const size_t A = (size_t)TOT * sizeof(float2);   // 16 MiB
    float2* t2 = (float2*)(ws);
    float2* B  = (float2*)(ws + A);
    float2* G  = (float2*)(ws + 2*A);
    unsigned int* keys = (unsigned int*)(ws + 3*A);              // 8 MiB
    c64* T  = (c64*)(ws + 3*A + (size_t)TOT*4);                  // 4 MiB
    c64* tw = (c64*)(ws + 3*A + (size_t)TOT*4 + (size_t)IMGE*16);
    unsigned int* hist = (unsigned int*)((char*)tw + 512*16);
    SelState* st = (SelState*)((char*)hist + 8192);

    float2* outW = (float2*)d_out;
    float2* outB = ((float2*)d_out) + TOT;

    hipMemsetAsync(hist, 0, 2048*sizeof(unsigned int), stream);
    k_init<<<IMGE/256, 256, 0, stream>>>(Q, zp, T, tw);

    auto sel = [&](){
        // pass-1 histogram fused into k_rowC
        k_scan<<<1,256,0,stream>>>(hist, st, 11, 2);
        k_hist<<<512,256,0,stream>>>((const uint4*)keys, hist, st, 21, 10, 11);
        k_scan<<<1,256,0,stream>>>(hist, st, 11, 0);
        k_hist<<<512,256,0,stream>>>((const uint4*)keys, hist, st, 10, 0, 10);
        k_scan<<<1,256,0,stream>>>(hist, st, 10, 1);
    };

    // ---- iteration 1: X=0 -> G=0, W=1 -> Qc=H ----
    k_colF<<<512,256,0,stream>>>(H, t2, tw);                    // t2 = colF(H)
    k_rowC<true><<<512,256,0,stream>>>(t2, G, B, keys, hist, tw);  // B = fft2(H) [+hist1]
    sel();
    k_rowD<true><<<512,256,0,stream>>>(B, st, G, T, t2, tw);    // E=B(1-m)*conjT, rowI
    k_colX<<<512,256,0,stream>>>(t2, tw);                       // colI -> thresh -> colF

    // ---- iterations 2..5 ----
    for (int iter = 2; iter <= 5; ++iter){
        k_rowFA<<<512,256,0,stream>>>(t2, B, st, T, G, tw);     // G=FX*T; rowI(G+Bm)
        k_colWQ<false><<<512,256,0,stream>>>(t2, H, outW, tw);  // W, Qc, colF(Qc)
        k_rowC<false><<<512,256,0,stream>>>(t2, G, B, keys, hist, tw);
        sel();
        k_rowD<false><<<512,256,0,stream>>>(B, st, G, T, t2, tw);
        k_colX<<<512,256,0,stream>>>(t2, tw);
    }

    // ---- iteration 6: only W and masked B needed ----
    k_rowFA<<<512,256,0,stream>>>(t2, B, st, T, G, tw);
    k_colWQ<true><<<512,256,0,stream>>>(t2, H, outW, tw);       // stores final W
    k_rowC<false><<<512,256,0,stream>>>(t2, G, B, keys, hist, tw);
    sel();
    k_outB<<<TOT/256,256,0,stream>>>(B, keys, st, outB);
}

// Round 18
// 726.613 us; speedup vs baseline: 1.3527x; 1.0047x over previous
//
#include <hip/hip_runtime.h>
#include <math.h>

// Problem constants
#define NIMG 8
#define MDIM 512
#define IMGE (MDIM*MDIM)        // 262144 per image
#define TOT  (NIMG*IMGE)        // 2097152 complex elements
#define BETA_K 4096
#define LAMD 0.1

typedef double2 c64;

struct SelState { unsigned int known; unsigned int rank; unsigned int thrkey; };

// Key derivation — used identically everywhere (rowC store, rowFA/rowD/outB recompute):
// from the ROUNDED f32 components, sqrt in f64, result cast to f32 bits.
__device__ __forceinline__ unsigned int keyOf(float bx, float by){
    return __float_as_uint((float)sqrt((double)bx*(double)bx + (double)by*(double)by));
}

// ---------------- LDS addressing ----------------
// Swizzle XORs bits 1..3 only (bit 0 preserved -> f64 pairs stay ordered-adjacent,
// ds_*_b128 vectorization preserved).
__device__ __forceinline__ int LPOS(int ln, int q){
    return (ln << 9) + (q ^ ((((q >> 4) ^ (2 * ln)) & 7) << 1));
}
__device__ __forceinline__ int rev8(int n){   // base-8 digit reversal of 9-bit index
    return ((n & 7) << 6) | (n & 56) | (n >> 6);
}
__device__ __forceinline__ int rde(int w, int k){ // rev8(8w+k)
    return 64*k + 8*(w & 7) + (w >> 3);
}

// ---------------- 8-point DFT in registers. INV=true: conjugate (inverse) ----------------
template<bool INV>
__device__ __forceinline__ void dft8(double* xr, double* xi){
    const double C = 0.70710678118654752440;
    double t0r=xr[0]+xr[4], t0i=xi[0]+xi[4];
    double t1r=xr[0]-xr[4], t1i=xi[0]-xi[4];
    double t2r=xr[2]+xr[6], t2i=xi[2]+xi[6];
    double t3r=xr[2]-xr[6], t3i=xi[2]-xi[6];
    double m3r = INV ? -t3i : t3i;
    double m3i = INV ?  t3r : -t3r;
    double E0r=t0r+t2r, E0i=t0i+t2i;
    double E2r=t0r-t2r, E2i=t0i-t2i;
    double E1r=t1r+m3r, E1i=t1i+m3i;
    double E3r=t1r-m3r, E3i=t1i-m3i;
    double u0r=xr[1]+xr[5], u0i=xi[1]+xi[5];
    double u1r=xr[1]-xr[5], u1i=xi[1]-xi[5];
    double u2r=xr[3]+xr[7], u2i=xi[3]+xi[7];
    double u3r=xr[3]-xr[7], u3i=xi[3]-xi[7];
    double n3r = INV ? -u3i : u3i;
    double n3i = INV ?  u3r : -u3r;
    double O0r=u0r+u2r, O0i=u0i+u2i;
    double O2r=u0r-u2r, O2i=u0i-u2i;
    double O1r=u1r+n3r, O1i=u1i+n3i;
    double O3r=u1r-n3r, O3i=u1i-n3i;
    double W1r = INV ? C*(O1r - O1i) : C*(O1r + O1i);
    double W1i = INV ? C*(O1r + O1i) : C*(O1i - O1r);
    double W2r = INV ? -O2i : O2i;
    double W2i = INV ?  O2r : -O2r;
    double W3r = INV ? -C*(O3r + O3i) : C*(O3i - O3r);
    double W3i = INV ? C*(O3r - O3i) : -C*(O3r + O3i);
    xr[0]=E0r+O0r; xi[0]=E0i+O0i;  xr[4]=E0r-O0r; xi[4]=E0i-O0i;
    xr[1]=E1r+W1r; xi[1]=E1i+W1i;  xr[5]=E1r-W1r; xi[5]=E1i-W1i;
    xr[2]=E2r+W2r; xi[2]=E2i+W2i;  xr[6]=E2r-W2r; xi[6]=E2i-W2i;
    xr[3]=E3r+W3r; xi[3]=E3i+W3i;  xr[7]=E3r-W3r; xi[7]=E3i-W3i;
}

// ================= ROW-path FFT helpers (register ends) =================
template<bool INV>
__device__ __forceinline__ void dit_from_regs(double (&ar)[2][8], double (&ai)[2][8],
                                              double* re, double* im, const c64* __restrict__ tw){
    const int t=threadIdx.x, w=t&63, l0=t>>6;
    #pragma unroll
    for (int h=0;h<2;++h){
        dft8<INV>(ar[h], ai[h]);
        const int ln=l0+4*h;
        #pragma unroll
        for (int k=0;k<8;++k){ int p=LPOS(ln,8*w+k); re[p]=ar[h][k]; im[p]=ai[h][k]; }
    }
    __syncthreads();
    {   // stage 1: groups 64g+j+8k, twiddle tw[8jk]
        const int g=w>>3, j=w&7;
        double wr[8], wi[8];
        #pragma unroll
        for (int k=1;k<8;++k){ c64 tv=tw[8*j*k]; wr[k]=tv.x; wi[k]=INV?-tv.y:tv.y; }
        #pragma unroll
        for (int h=0;h<2;++h){
            const int ln=l0+4*h;
            double xr[8], xi[8];
            #pragma unroll
            for (int k=0;k<8;++k){ int p=LPOS(ln,64*g+j+8*k); double a=re[p],b=im[p];
                if(k==0){xr[0]=a; xi[0]=b;} else {xr[k]=a*wr[k]-b*wi[k]; xi[k]=a*wi[k]+b*wr[k];} }
            dft8<INV>(xr,xi);
            #pragma unroll
            for (int k=0;k<8;++k){ int p=LPOS(ln,64*g+j+8*k); re[p]=xr[k]; im[p]=xi[k]; }
        }
    }
    __syncthreads();
    {   // stage 2 -> regs: groups j+64k, twiddle tw[jk]
        const int j=w;
        double wr[8], wi[8];
        #pragma unroll
        for (int k=1;k<8;++k){ c64 tv=tw[j*k]; wr[k]=tv.x; wi[k]=INV?-tv.y:tv.y; }
        #pragma unroll
        for (int h=0;h<2;++h){
            const int ln=l0+4*h;
            #pragma unroll
            for (int k=0;k<8;++k){ int p=LPOS(ln,j+64*k); double a=re[p],b=im[p];
                if(k==0){ar[h][0]=a; ai[h][0]=b;} else {ar[h][k]=a*wr[k]-b*wi[k]; ai[h][k]=a*wi[k]+b*wr[k];} }
            dft8<INV>(ar[h], ai[h]);
        }
    }
}

template<bool INV>
__device__ __forceinline__ void dif_to_regs(double (&ar)[2][8], double (&ai)[2][8],
                                            double* re, double* im, const c64* __restrict__ tw){
    const int t=threadIdx.x, w=t&63, l0=t>>6;
    {   // stage A (from regs): dft8, post-twiddle tw[w*k], write at j+64k
        const int j=w;
        double wr[8], wi[8];
        #pragma unroll
        for (int k=1;k<8;++k){ c64 tv=tw[j*k]; wr[k]=tv.x; wi[k]=INV?-tv.y:tv.y; }
        #pragma unroll
        for (int h=0;h<2;++h){
            dft8<INV>(ar[h], ai[h]);
            const int ln=l0+4*h;
            #pragma unroll
            for (int k=0;k<8;++k){
                int p=LPOS(ln,j+64*k);
                if(k==0){ re[p]=ar[h][0]; im[p]=ai[h][0]; }
                else { re[p]=ar[h][k]*wr[k]-ai[h][k]*wi[k]; im[p]=ar[h][k]*wi[k]+ai[h][k]*wr[k]; }
            }
        }
    }
    __syncthreads();
    {   // stage B: groups 64g+j+8k, post-twiddle tw[8jk]
        const int g=w>>3, j=w&7;
        double wr[8], wi[8];
        #pragma unroll
        for (int k=1;k<8;++k){ c64 tv=tw[8*j*k]; wr[k]=tv.x; wi[k]=INV?-tv.y:tv.y; }
        #pragma unroll
        for (int h=0;h<2;++h){
            const int ln=l0+4*h;
            double xr[8], xi[8];
            #pragma unroll
            for (int k=0;k<8;++k){ int p=LPOS(ln,64*g+j+8*k); xr[k]=re[p]; xi[k]=im[p]; }
            dft8<INV>(xr,xi);
            #pragma unroll
            for (int k=0;k<8;++k){
                int p=LPOS(ln,64*g+j+8*k);
                if(k==0){ re[p]=xr[0]; im[p]=xi[0]; }
                else { re[p]=xr[k]*wr[k]-xi[k]*wi[k]; im[p]=xr[k]*wi[k]+xi[k]*wr[k]; }
            }
        }
    }
    __syncthreads();
    // stage C -> regs (no twiddle)
    #pragma unroll
    for (int h=0;h<2;++h){
        const int ln=l0+4*h;
        #pragma unroll
        for (int k=0;k<8;++k){ int p=LPOS(ln,8*w+k); ar[h][k]=re[p]; ai[h][k]=im[p]; }
        dft8<INV>(ar[h], ai[h]);
    }
}

// ================= COL-path FFT (full-LDS) =================
template<bool INV>
__device__ void r8_dit(double* re, double* im, const c64* __restrict__ tw){
    const int t = threadIdx.x;
    const int w = t & 63;
    const int l0 = t >> 6;
    __syncthreads();
    #pragma unroll
    for (int h = 0; h < 2; ++h){
        const int ln = l0 + 4*h;
        double xr[8], xi[8];
        #pragma unroll
        for (int k = 0; k < 8; ++k){ int p = LPOS(ln, 8*w + k); xr[k]=re[p]; xi[k]=im[p]; }
        dft8<INV>(xr, xi);
        #pragma unroll
        for (int k = 0; k < 8; ++k){ int p = LPOS(ln, 8*w + k); re[p]=xr[k]; im[p]=xi[k]; }
    }
    {
        const int g = w >> 3, j = w & 7;
        double wr[8], wi[8];
        #pragma unroll
        for (int k = 1; k < 8; ++k){ c64 tv = tw[8*j*k]; wr[k]=tv.x; wi[k]= INV ? -tv.y : tv.y; }
        __syncthreads();
        #pragma unroll
        for (int h = 0; h < 2; ++h){
            const int ln = l0 + 4*h;
            double xr[8], xi[8];
            #pragma unroll
            for (int k = 0; k < 8; ++k){
                int p = LPOS(ln, 64*g + j + 8*k); double a=re[p], b=im[p];
                if (k == 0){ xr[0]=a; xi[0]=b; }
                else { xr[k]=a*wr[k]-b*wi[k]; xi[k]=a*wi[k]+b*wr[k]; }
            }
            dft8<INV>(xr, xi);
            #pragma unroll
            for (int k = 0; k < 8; ++k){ int p = LPOS(ln, 64*g + j + 8*k); re[p]=xr[k]; im[p]=xi[k]; }
        }
    }
    {
        const int j = w;
        double wr[8], wi[8];
        #pragma unroll
        for (int k = 1; k < 8; ++k){ c64 tv = tw[j*k]; wr[k]=tv.x; wi[k]= INV ? -tv.y : tv.y; }
        __syncthreads();
        #pragma unroll
        for (int h = 0; h < 2; ++h){
            const int ln = l0 + 4*h;
            double xr[8], xi[8];
            #pragma unroll
            for (int k = 0; k < 8; ++k){
                int p = LPOS(ln, j + 64*k); double a=re[p], b=im[p];
                if (k == 0){ xr[0]=a; xi[0]=b; }
                else { xr[k]=a*wr[k]-b*wi[k]; xi[k]=a*wi[k]+b*wr[k]; }
            }
            dft8<INV>(xr, xi);
            #pragma unroll
            for (int k = 0; k < 8; ++k){ int p = LPOS(ln, j + 64*k); re[p]=xr[k]; im[p]=xi[k]; }
        }
    }
}

template<bool INV>
__device__ void r8_dif(double* re, double* im, const c64* __restrict__ tw){
    const int t = threadIdx.x;
    const int w = t & 63;
    const int l0 = t >> 6;
    {
        const int j = w;
        double wr[8], wi[8];
        #pragma unroll
        for (int k = 1; k < 8; ++k){ c64 tv = tw[j*k]; wr[k]=tv.x; wi[k]= INV ? -tv.y : tv.y; }
        __syncthreads();
        #pragma unroll
        for (int h = 0; h < 2; ++h){
            const int ln = l0 + 4*h;
            double xr[8], xi[8];
            #pragma unroll
            for (int k = 0; k < 8; ++k){ int p = LPOS(ln, j + 64*k); xr[k]=re[p]; xi[k]=im[p]; }
            dft8<INV>(xr, xi);
            #pragma unroll
            for (int k = 0; k < 8; ++k){
                int p = LPOS(ln, j + 64*k);
                if (k == 0){ re[p]=xr[0]; im[p]=xi[0]; }
                else { re[p]=xr[k]*wr[k]-xi[k]*wi[k]; im[p]=xr[k]*wi[k]+xi[k]*wr[k]; }
            }
        }
    }
    {
        const int g = w >> 3, j = w & 7;
        double wr[8], wi[8];
        #pragma unroll
        for (int k = 1; k < 8; ++k){ c64 tv = tw[8*j*k]; wr[k]=tv.x; wi[k]= INV ? -tv.y : tv.y; }
        __syncthreads();
        #pragma unroll
        for (int h = 0; h < 2; ++h){
            const int ln = l0 + 4*h;
            double xr[8], xi[8];
            #pragma unroll
            for (int k = 0; k < 8; ++k){ int p = LPOS(ln, 64*g + j + 8*k); xr[k]=re[p]; xi[k]=im[p]; }
            dft8<INV>(xr, xi);
            #pragma unroll
            for (int k = 0; k < 8; ++k){
                int p = LPOS(ln, 64*g + j + 8*k);
                if (k == 0){ re[p]=xr[0]; im[p]=xi[0]; }
                else { re[p]=xr[k]*wr[k]-xi[k]*wi[k]; im[p]=xr[k]*wi[k]+xi[k]*wr[k]; }
            }
        }
    }
    __syncthreads();
    #pragma unroll
    for (int h = 0; h < 2; ++h){
        const int ln = l0 + 4*h;
        double xr[8], xi[8];
        #pragma unroll
        for (int k = 0; k < 8; ++k){ int p = LPOS(ln, 8*w + k); xr[k]=re[p]; xi[k]=im[p]; }
        dft8<INV>(xr, xi);
        #pragma unroll
        for (int k = 0; k < 8; ++k){ int p = LPOS(ln, 8*w + k); re[p]=xr[k]; im[p]=xi[k]; }
    }
}

__device__ __forceinline__ void col_load32(const float2* __restrict__ src, size_t base,
                                           double* re, double* im){
    const int t = threadIdx.x;
    #pragma unroll
    for (int it = 0; it < 16; ++it){
        int idx = it*256 + t; int ln = idx & 7, e = idx >> 3;
        float2 v = src[base + ln + (size_t)e*512];
        int p = LPOS(ln, rev8(e));
        re[p] = (double)v.x; im[p] = (double)v.y;
    }
}

// ---------------- init: T = exp(i*(z/WL)*Q) (stored f32), twiddles (f64) ----------------
__global__ __launch_bounds__(256) void k_init(const float* __restrict__ Q,
                                              const float* __restrict__ zp,
                                              float2* __restrict__ T,
                                              c64* __restrict__ tw){
    int i = blockIdx.x*256 + threadIdx.x;
    if (i < IMGE){
        double a = ((double)zp[0] / 6.37e-07) * (double)Q[i];
        T[i] = make_float2((float)cos(a), (float)sin(a));
    }
    if (i < 512){
        double a = -6.283185307179586476925286766559 * ((double)i / 512.0);
        tw[i] = make_double2(cos(a), sin(a));
    }
}

// ---------------- k_colF (iter 1): forward col FFT of H -> t2 ----------------
__global__ __launch_bounds__(256,2) void k_colF(const float2* __restrict__ H,
                                                float2* __restrict__ t2,
                                                const c64* __restrict__ tw){
    __shared__ double re[4096]; __shared__ double im[4096];
    const int t = threadIdx.x, blk = blockIdx.x;
    const size_t base = (size_t)(blk >> 6) * IMGE + (size_t)(blk & 63) * 8;
    col_load32(H, base, re, im);
    r8_dit<false>(re, im, tw);
    __syncthreads();
    #pragma unroll
    for (int it = 0; it < 16; ++it){
        int idx = it*256 + t; int ln = idx & 7, e = idx >> 3;
        int p = LPOS(ln, e);
        t2[base + ln + (size_t)e*512] = make_float2((float)re[p], (float)im[p]);
    }
}

// ---------------- k_rowFA: rowF(X) -> G=FX*T (store); then rowI(G + Bm) -> t2 ----------------
__global__ __launch_bounds__(256,2) void k_rowFA(float2* __restrict__ t2,
                                                 const float2* __restrict__ B,
                                                 const SelState* __restrict__ st,
                                                 const float2* __restrict__ T,
                                                 float2* __restrict__ G,
                                                 const c64* __restrict__ tw){
    __shared__ double re[4096]; __shared__ double im[4096];
    const int t = threadIdx.x, blk = blockIdx.x;
    const int w = t & 63, l0 = t >> 6;
    const size_t base = (size_t)blk * 4096;
    const unsigned int thr = st->thrkey;
    double ar[2][8], ai[2][8];
    #pragma unroll
    for (int h=0;h<2;++h){ const int ln=l0+4*h;
        #pragma unroll
        for (int k=0;k<8;++k){ float2 v = t2[base + ln*512 + rde(w,k)];
            ar[h][k]=(double)v.x; ai[h][k]=(double)v.y; } }
    dit_from_regs<false>(ar, ai, re, im, tw);      // rowF of colF(X): full fft2(X) rows
    #pragma unroll
    for (int h=0;h<2;++h){
        const int ln=l0+4*h;
        const int u = (blk & 63) * 8 + ln;
        #pragma unroll
        for (int k=0;k<8;++k){
            const int e = w + 64*k;
            size_t addr = base + ln*512 + e;
            float2 tv = T[u*512 + e];
            double txr = (double)tv.x, tyr = (double)tv.y;
            double xr = ar[h][k], xi = ai[h][k];
            double gr = xr*txr - xi*tyr;           // G = fft2(X)*T
            double gi = xr*tyr + xi*txr;
            G[addr] = make_float2((float)gr, (float)gi);
            float2 b = B[addr];
            bool keep = keyOf(b.x, b.y) >= thr;    // Bm = top-k kept (key recomputed)
            ar[h][k] = gr + (keep ? (double)b.x : 0.0);
            ai[h][k] = gi + (keep ? (double)b.y : 0.0);
        }
    }
    dif_to_regs<true>(ar, ai, re, im, tw);         // rowI(G + Bm)
    const double sc = 1.0/512.0;
    #pragma unroll
    for (int h=0;h<2;++h){ const int ln=l0+4*h;
        #pragma unroll
        for (int k=0;k<8;++k)
            t2[base + ln*512 + rde(w,k)] = make_float2((float)(ar[h][k]*sc), (float)(ai[h][k]*sc)); }
}

// ---------------- kB: colI -> W=normalize(Z) -> Qc=H*W -> colF(Qc) ----------------
template<bool FINAL>
__global__ __launch_bounds__(256,2) void k_colWQ(float2* __restrict__ t2,
                                                 const float2* __restrict__ H,
                                                 float2* __restrict__ outW,
                                                 const c64* __restrict__ tw){
    __shared__ double re[4096]; __shared__ double im[4096];
    const int t = threadIdx.x, blk = blockIdx.x;
    const size_t base = (size_t)(blk >> 6) * IMGE + (size_t)(blk & 63) * 8;
    col_load32(t2, base, re, im);
    r8_dit<true>(re, im, tw);          // inverse col FFT (unscaled here)
    __syncthreads();
    const double sc = 1.0/512.0;
    #pragma unroll
    for (int it = 0; it < 16; ++it){
        int idx = it*256 + t; int ln = idx & 7, e = idx >> 3;
        size_t addr = base + ln + (size_t)e*512;
        int p = LPOS(ln, e);
        double zr = re[p]*sc, zi = im[p]*sc;   // Z = convXT + IB (spatial)
        double m = sqrt(zr*zr + zi*zi);
        double d = (m == 0.0) ? 1.0 : m;
        double wx = zr/d, wy = zi/d;           // W = normalize(Z)
        if (FINAL) outW[addr] = make_float2((float)wx, (float)wy);
        float2 h = H[addr];
        re[p] = (double)h.x*wx - (double)h.y*wy;   // Qc = H*W
        im[p] = (double)h.x*wy + (double)h.y*wx;
    }
    r8_dif<false>(re, im, tw);         // forward col FFT of Qc
    __syncthreads();
    #pragma unroll
    for (int it = 0; it < 16; ++it){
        int idx = it*256 + t; int ln = idx & 7, e = idx >> 3;
        int p = LPOS(ln, rev8(e));
        t2[base + ln + (size_t)e*512] = make_float2((float)re[p], (float)im[p]);
    }
}

// ---------------- kC: rowF -> B = FQc - G -> store B/keys + fused hist pass-1 ----------------
template<bool G0>
__global__ __launch_bounds__(256,2) void k_rowC(const float2* __restrict__ t2,
                                                const float2* __restrict__ G,
                                                float2* __restrict__ B,
                                                unsigned int* __restrict__ keys,
                                                unsigned int* __restrict__ hist,
                                                const c64* __restrict__ tw){
    __shared__ double re[4096]; __shared__ double im[4096];
    const int t = threadIdx.x, blk = blockIdx.x;
    const int w = t & 63, l0 = t >> 6;
    const size_t base = (size_t)blk * 4096;
    double ar[2][8], ai[2][8];
    #pragma unroll
    for (int h=0;h<2;++h){ const int ln=l0+4*h;
        #pragma unroll
        for (int k=0;k<8;++k){ float2 v = t2[base + ln*512 + rde(w,k)];
            ar[h][k]=(double)v.x; ai[h][k]=(double)v.y; } }
    dit_from_regs<false>(ar, ai, re, im, tw);
    __syncthreads();                   // stage-2 LDS reads done -> reuse re as hist
    unsigned int* lh = reinterpret_cast<unsigned int*>(re);
    for (int b = t; b < 2048; b += 256) lh[b] = 0u;
    __syncthreads();
    #pragma unroll
    for (int h=0;h<2;++h){
        const int ln=l0+4*h;
        #pragma unroll
        for (int k=0;k<8;++k){
            size_t addr = base + ln*512 + (w + 64*k);
            double br = ar[h][k], bi = ai[h][k];
            if (!G0){ float2 g = G[addr]; br -= (double)g.x; bi -= (double)g.y; }
            float fbr = (float)br, fbi = (float)bi;
            B[addr] = make_float2(fbr, fbi);
            unsigned int key = keyOf(fbr, fbi);    // from ROUNDED f32 (matches consumers)
            keys[addr] = key;
            atomicAdd(&lh[key >> 21], 1u);
        }
    }
    __syncthreads();
    for (int b = t; b < 2048; b += 256){
        unsigned int v = lh[b];
        if (v) atomicAdd(&hist[b], v);
    }
}

// ---------------- kD: E = (B*(1-mask) + G)*conj(T) -> rowI -> t2 (x1/512) ----------------
template<bool G0>
__global__ __launch_bounds__(256,2) void k_rowD(const float2* __restrict__ B,
                                                const SelState* __restrict__ st,
                                                const float2* __restrict__ G,
                                                const float2* __restrict__ T,
                                                float2* __restrict__ t2,
                                                const c64* __restrict__ tw){
    __shared__ double re[4096]; __shared__ double im[4096];
    const int t = threadIdx.x, blk = blockIdx.x;
    const int w = t & 63, l0 = t >> 6;
    const size_t base = (size_t)blk * 4096;
    const unsigned int thr = st->thrkey;
    double ar[2][8], ai[2][8];
    #pragma unroll
    for (int h=0;h<2;++h){
        const int ln=l0+4*h;
        const int u = (blk & 63) * 8 + ln;
        #pragma unroll
        for (int k=0;k<8;++k){
            const int e = w + 64*k;
            size_t addr = base + ln*512 + e;
            float2 b = B[addr];
            bool lo = keyOf(b.x, b.y) < thr;      // complement of top-k mask (key recomputed)
            double vr = lo ? (double)b.x : 0.0;
            double vi = lo ? (double)b.y : 0.0;
            if (!G0){ float2 g = G[addr]; vr += (double)g.x; vi += (double)g.y; }
            float2 tv = T[u*512 + e];
            double txr = (double)tv.x, tyr = (double)tv.y;
            ar[h][k] = vr*txr + vi*tyr;           // * conj(T)
            ai[h][k] = vi*txr - vr*tyr;
        }
    }
    dif_to_regs<true>(ar, ai, re, im, tw);
    const double sc = 1.0/512.0;
    #pragma unroll
    for (int h=0;h<2;++h){ const int ln=l0+4*h;
        #pragma unroll
        for (int k=0;k<8;++k)
            t2[base + ln*512 + rde(w,k)] = make_float2((float)(ar[h][k]*sc), (float)(ai[h][k]*sc)); }
}

// ---------------- kE: colI -> X = inp1*(|inp1|>LAM) -> colF(X) ----------------
__global__ __launch_bounds__(256,2) void k_colX(float2* __restrict__ t2,
                                                const c64* __restrict__ tw){
    __shared__ double re[4096]; __shared__ double im[4096];
    const int t = threadIdx.x, blk = blockIdx.x;
    const size_t base = (size_t)(blk >> 6) * IMGE + (size_t)(blk & 63) * 8;
    col_load32(t2, base, re, im);
    r8_dit<true>(re, im, tw);
    __syncthreads();
    const double sc = 1.0/512.0;
    #pragma unroll
    for (int it = 0; it < 16; ++it){
        int idx = it*256 + t;
        int p = LPOS(idx & 7, idx >> 3);
        double vr = re[p]*sc, vi = im[p]*sc;      // inp1
        double m = sqrt(vr*vr + vi*vi);
        bool keep = m > LAMD;
        re[p] = keep ? vr : 0.0;
        im[p] = keep ? vi : 0.0;
    }
    r8_dif<false>(re, im, tw);
    __syncthreads();
    #pragma unroll
    for (int it = 0; it < 16; ++it){
        int idx = it*256 + t; int ln = idx & 7, e = idx >> 3;
        int p = LPOS(ln, rev8(e));
        t2[base + ln + (size_t)e*512] = make_float2((float)re[p], (float)im[p]);
    }
}

// ---------------- final masked B -> d_out second half (key recomputed from B) ----------------
__global__ __launch_bounds__(256) void k_outB(const float2* __restrict__ B,
                                              const SelState* __restrict__ st,
                                              float2* __restrict__ outB){
    int i = blockIdx.x*256 + threadIdx.x;
    float2 v = B[i];
    if (keyOf(v.x, v.y) < st->thrkey) v = make_float2(0.0f, 0.0f);
    outB[i] = v;
}

// ---------------- radix select: filtered histogram (uint4 reads) + parallel scan ----------------
__global__ __launch_bounds__(256) void k_hist(const uint4* __restrict__ keys4,
                                              unsigned int* __restrict__ hist,
                                              const SelState* __restrict__ st,
                                              int shiftHi, int shift, int dbits){
    __shared__ unsigned int lh[2048];
    int t = threadIdx.x;
    int nd = 1 << dbits;
    for (int b = t; b < nd; b += 256) lh[b] = 0u;
    __syncthreads();
    unsigned known = st->known;
    unsigned msk = (unsigned)((1u << dbits) - 1u);
    const unsigned n4 = TOT/4;
    for (unsigned i = blockIdx.x*256 + t; i < n4; i += gridDim.x*256){
        uint4 v = keys4[i];
        if ((v.x >> shiftHi) == known) atomicAdd(&lh[(v.x >> shift) & msk], 1u);
        if ((v.y >> shiftHi) == known) atomicAdd(&lh[(v.y >> shift) & msk], 1u);
        if ((v.z >> shiftHi) == known) atomicAdd(&lh[(v.z >> shift) & msk], 1u);
        if ((v.w >> shiftHi) == known) atomicAdd(&lh[(v.w >> shift) & msk], 1u);
    }
    __syncthreads();
    for (int b = t; b < nd; b += 256){
        unsigned v = lh[b];
        if (v) atomicAdd(&hist[b], v);
    }
}

// mode: 2=first pass (rank=BETA, known=0), 0=middle, 1=last (writes thrkey).
__global__ __launch_bounds__(256) void k_scan(unsigned int* __restrict__ hist,
                                              SelState* __restrict__ st,
                                              int dbits, int mode){
    __shared__ unsigned int s[256];
    const int t = threadIdx.x;
    const int nd = 1 << dbits;
    const int per = nd >> 8;
    unsigned c[8];
    unsigned local = 0u;
    const int b0 = t * per;
    #pragma unroll
    for (int j = 0; j < 8; ++j){
        unsigned v = 0u;
        if (j < per){ v = hist[b0 + j]; hist[b0 + j] = 0u; }
        c[j] = v; local += v;
    }
    unsigned rank = (mode == 2) ? (unsigned)BETA_K : st->rank;
    s[t] = local;
    __syncthreads();
    #pragma unroll
    for (int off = 1; off < 256; off <<= 1){
        unsigned add = (t + off < 256) ? s[t + off] : 0u;
        __syncthreads();
        s[t] += add;
        __syncthreads();
    }
    unsigned stot   = s[t];
    unsigned sAfter = (t < 255) ? s[t + 1] : 0u;
    if (sAfter < rank && stot >= rank){
        unsigned cum = sAfter;
        int j = per - 1;
        #pragma unroll
        for (int k = 7; k >= 0; --k){
            if (k > per - 1) continue;
            j = k;
            if (cum + c[k] >= rank) break;
            cum += c[k];
        }
        st->rank = rank - cum;
        unsigned kn = (mode == 2) ? 0u : st->known;
        unsigned nk = (kn << dbits) | (unsigned)(b0 + j);
        st->known = nk;
        if (mode == 1) st->thrkey = nk;
    }
}

// ---------------- orchestration ----------------
// Freq-domain formulation: G = fft2(X)*T.
//   W = normalize(ifft2(G + Bm_prev)); B = fft2(H*W) - G
//   E = (B*(1-mask) + G)*conj(T); X = thresh(ifft2(E)); G' = fft2(X)*T (fused into rowFA)
// ws (f32 arrays, f64 twiddles): t2 16M | B 16M | G 16M | keys 8M | T 2M | tw | hist | st
extern "C" void kernel_launch(void* const* d_in, const int* in_sizes, int n_in,
                              void* d_out, int out_size, void* d_ws, size_t ws_size,
                              hipStream_t stream){
    (void)in_sizes; (void)n_in; (void)out_size; (void)ws_size;
    const float2* H = (const float2*)d_in[0];
    const float*  Q = (const float*)d_in[1];
    const float*  zp = (const float*)d_in[2];

    char* ws = (char*)d_ws;
    const size_t A = (size_t)TOT * sizeof(float2);   // 16 MiB
    float2* t2 = (float2*)(ws);
    float2* B  = (float2*)(ws + A);
    float2* G  = (float2*)(ws + 2*A);
    unsigned int* keys = (unsigned int*)(ws + 3*A);              // 8 MiB
    float2* T  = (float2*)(ws + 3*A + (size_t)TOT*4);            // 2 MiB (f32)
    c64* tw = (c64*)(ws + 3*A + (size_t)TOT*4 + (size_t)IMGE*8);
    unsigned int* hist = (unsigned int*)((char*)tw + 512*16);
    SelState* st = (SelState*)((char*)hist + 8192);

    float2* outW = (float2*)d_out;
    float2* outB = ((float2*)d_out) + TOT;

    hipMemsetAsync(hist, 0, 2048*sizeof(unsigned int), stream);
    k_init<<<IMGE/256, 256, 0, stream>>>(Q, zp, T, tw);

    auto sel = [&](){
        // pass-1 histogram fused into k_rowC
        k_scan<<<1,256,0,stream>>>(hist, st, 11, 2);
        k_hist<<<512,256,0,stream>>>((const uint4*)keys, hist, st, 21, 10, 11);
        k_scan<<<1,256,0,stream>>>(hist, st, 11, 0);
        k_hist<<<512,256,0,stream>>>((const uint4*)keys, hist, st, 10, 0, 10);
        k_scan<<<1,256,0,stream>>>(hist, st, 10, 1);
    };

    // ---- iteration 1: X=0 -> G=0, W=1 -> Qc=H ----
    k_colF<<<512,256,0,stream>>>(H, t2, tw);                    // t2 = colF(H)
    k_rowC<true><<<512,256,0,stream>>>(t2, G, B, keys, hist, tw);  // B = fft2(H) [+hist1]
    sel();
    k_rowD<true><<<512,256,0,stream>>>(B, st, G, T, t2, tw);    // E=B(1-m)*conjT, rowI
    k_colX<<<512,256,0,stream>>>(t2, tw);                       // colI -> thresh -> colF

    // ---- iterations 2..5 ----
    for (int iter = 2; iter <= 5; ++iter){
        k_rowFA<<<512,256,0,stream>>>(t2, B, st, T, G, tw);     // G=FX*T; rowI(G+Bm)
        k_colWQ<false><<<512,256,0,stream>>>(t2, H, outW, tw);  // W, Qc, colF(Qc)
        k_rowC<false><<<512,256,0,stream>>>(t2, G, B, keys, hist, tw);
        sel();
        k_rowD<false><<<512,256,0,stream>>>(B, st, G, T, t2, tw);
        k_colX<<<512,256,0,stream>>>(t2, tw);
    }

    // ---- iteration 6: only W and masked B needed ----
    k_rowFA<<<512,256,0,stream>>>(t2, B, st, T, G, tw);
    k_colWQ<true><<<512,256,0,stream>>>(t2, H, outW, tw);       // stores final W
    k_rowC<false><<<512,256,0,stream>>>(t2, G, B, keys, hist, tw);
    sel();
    k_outB<<<TOT/256,256,0,stream>>>(B, st, outB);
}